// Round 1
// baseline (991.805 us; speedup 1.0000x reference)
//
#include <hip/hip_runtime.h>

typedef _Float16 f16;
typedef _Float16 f16x4 __attribute__((ext_vector_type(4)));
typedef _Float16 f16x8 __attribute__((ext_vector_type(8)));
typedef float    f32x4 __attribute__((ext_vector_type(4)));

__device__ __forceinline__ float4 ld4h(const f16* p) {
  f16x4 t = *(const f16x4*)p;
  return make_float4((float)t[0], (float)t[1], (float)t[2], (float)t[3]);
}

// ===================== pack: f32 -> f16 casts (x + all GEMM weights) =====================
__global__ __launch_bounds__(256) void cast_kernel(
    const float* __restrict__ x, const float* __restrict__ Wq, const float* __restrict__ Wk,
    const float* __restrict__ Wv, const float* __restrict__ Wo, const float* __restrict__ Wf,
    const float* __restrict__ Wd2,
    f16* __restrict__ x_h, f16* __restrict__ wqkv, f16* __restrict__ wo_h,
    f16* __restrict__ wf_h, f16* __restrict__ wd2h, int N)
{
  const int n0 = N * 64;  // x elements in float4 units
  const int total = n0 + 147456 + 49152 + 49152 + 24576;
  for (int i = blockIdx.x * 256 + threadIdx.x; i < total; i += gridDim.x * 256) {
    const float4* sp; f16x4* dp;
    int k = i;
    if (k < n0) { sp = (const float4*)x + k; dp = (f16x4*)x_h + k; }
    else {
      k -= n0;
      if (k < 147456) {  // wqkv: [s][q|k|v][256][256] -> [s][768][256]
        int s = k / 49152, r = k % 49152, m = r / 16384, off = r % 16384;
        const float* w = (m == 0) ? Wq : (m == 1) ? Wk : Wv;
        sp = (const float4*)(w + s * 65536) + off;
        dp = (f16x4*)wqkv + k;
      } else {
        k -= 147456;
        if (k < 49152) { sp = (const float4*)Wo + k; dp = (f16x4*)wo_h + k; }
        else {
          k -= 49152;
          if (k < 49152) { sp = (const float4*)Wf + k; dp = (f16x4*)wf_h + k; }
          else { k -= 49152; sp = (const float4*)Wd2 + k; dp = (f16x4*)wd2h + k; }
        }
      }
    }
    float4 v = *sp;
    f16x4 o; o[0] = (f16)v.x; o[1] = (f16)v.y; o[2] = (f16)v.z; o[3] = (f16)v.w;
    *dp = o;
  }
}

// ===================== enc lookup table: [3][100][16] =====================
__global__ __launch_bounds__(256) void enc_kernel(
    const float* __restrict__ dist_emb, const float* __restrict__ dir_emb,
    const float* __restrict__ Wsp1, const float* __restrict__ bsp1,
    const float* __restrict__ Wsp2, const float* __restrict__ bsp2,
    float* __restrict__ enc_tab)
{
  int id = blockIdx.x * 256 + threadIdx.x;
  if (id >= 3 * 1600) return;
  int s = id / 1600, c = id % 1600, db = c >> 4, ab = c & 15;
  const float* de = dist_emb + (size_t)(s * 100 + db) * 16;
  const float* ae = dir_emb + (size_t)(s * 16 + ab) * 16;
  const float* w1 = Wsp1 + s * 1024;
  const float* b1 = bsp1 + s * 32;
  const float* w2 = Wsp2 + s * 32;
  float enc = bsp2[s];
  for (int j = 0; j < 32; ++j) {
    float a = b1[j];
    const float* wr = w1 + j * 32;
#pragma unroll
    for (int i = 0; i < 16; ++i) a += de[i] * wr[i];
#pragma unroll
    for (int i = 0; i < 16; ++i) a += ae[i] * wr[16 + i];
    enc += fmaxf(a, 0.0f) * w2[j];
  }
  enc_tab[id] = enc;
}

// ===================== degree histograms =====================
__global__ __launch_bounds__(256) void hist_kernel(const int* __restrict__ eidx,
                                                   int* deg_i, int* indeg_i, int E)
{
  int e = blockIdx.x * 256 + threadIdx.x;
  if (e >= E) return;
  atomicAdd(&deg_i[eidx[e]], 1);
  atomicAdd(&indeg_i[eidx[E + e]], 1);
}

// ===================== single-block exclusive scan of both histograms =====================
__global__ __launch_bounds__(1024) void scan_kernel(const int* __restrict__ indeg,
                                                    const int* __restrict__ deg,
                                                    int* dptr, int* sptr, int N)
{
  __shared__ int lds[1024];
  const int tid = threadIdx.x;
  for (int pass = 0; pass < 2; ++pass) {
    const int* in = pass ? deg : indeg;
    int* out = pass ? sptr : dptr;
    int base = tid * 16;
    int loc[16];
    int sum = 0;
#pragma unroll
    for (int j = 0; j < 16; ++j) {
      int v = (base + j < N) ? in[base + j] : 0;
      loc[j] = sum; sum += v;
    }
    lds[tid] = sum;
    __syncthreads();
    for (int off = 1; off < 1024; off <<= 1) {
      int t = (tid >= off) ? lds[tid - off] : 0;
      __syncthreads();
      lds[tid] += t;
      __syncthreads();
    }
    int prev = tid ? lds[tid - 1] : 0;
#pragma unroll
    for (int j = 0; j < 16; ++j)
      if (base + j < N) out[base + j] = prev + loc[j];
    if (tid == 1023) out[N] = lds[1023];
    __syncthreads();
  }
}

// ===================== CSR scatter + per-edge geometry bins =====================
__global__ __launch_bounds__(256) void scatter_kernel(
    const int* __restrict__ eidx, const float* __restrict__ coords,
    const int* __restrict__ dptr, const int* __restrict__ sptr,
    int* fill_d, int* fill_s, int2* __restrict__ erec, int* __restrict__ sdst, int E)
{
  int e = blockIdx.x * 256 + threadIdx.x;
  if (e >= E) return;
  int s = eidx[e], d = eidx[E + e];
  float rx = coords[2 * s] - coords[2 * d];
  float ry = coords[2 * s + 1] - coords[2 * d + 1];
  float dist = sqrtf(rx * rx + ry * ry);
  float ang = atan2f(ry, rx);
  int ab = (int)((ang + 3.14159265358979323846f) / 6.28318530717958647692f * 15.0f);
  ab = ab < 0 ? 0 : (ab > 15 ? 15 : ab);
  int b0 = (int)((dist / 500.0f) * 99.0f);  b0 = b0 < 0 ? 0 : (b0 > 99 ? 99 : b0);
  int b1 = (int)((dist / 1000.0f) * 99.0f); b1 = b1 < 0 ? 0 : (b1 > 99 ? 99 : b1);
  int b2 = (int)((dist / 2000.0f) * 99.0f); b2 = b2 < 0 ? 0 : (b2 > 99 ? 99 : b2);
  unsigned pb = (unsigned)b0 | ((unsigned)b1 << 7) | ((unsigned)b2 << 14) | ((unsigned)ab << 21);
  int pd = dptr[d] + atomicAdd(&fill_d[d], 1);
  erec[pd] = make_int2(s, (int)pb);
  int ps = sptr[s] + atomicAdd(&fill_s[s], 1);
  sdst[ps] = d;
}

// ===================== spatial density: O(N^2) radius count =====================
__global__ __launch_bounds__(256) void sp_kernel(const float* __restrict__ coords,
                                                 int* __restrict__ sp_i, int N)
{
  __shared__ float2 cj[2048];
  int j0 = blockIdx.y * 2048;
  int jn = N - j0; if (jn > 2048) jn = 2048;
  for (int j = threadIdx.x; j < jn; j += 256) cj[j] = ((const float2*)coords)[j0 + j];
  __syncthreads();
  int i = blockIdx.x * 256 + threadIdx.x;
  if (i >= N) return;
  float cx = coords[2 * i], cy = coords[2 * i + 1];
  int cnt = 0;
  for (int j = 0; j < jn; ++j) {
    float dx = cx - cj[j].x, dy = cy - cj[j].y;
    float dd = sqrtf(dx * dx + dy * dy);
    cnt += (dd <= 50.0f) ? 1 : 0;
  }
  atomicAdd(&sp_i[i], cnt);
}

// ===================== fvar (local feature variance) + global maxes =====================
__global__ __launch_bounds__(256) void fvar_kernel(
    const float* __restrict__ x, const f16* __restrict__ x_h,
    const int* __restrict__ sptr, const int* __restrict__ sdst,
    const int* __restrict__ sp_i, float* __restrict__ fvar, unsigned* maxc, int N)
{
  int wv = threadIdx.x >> 6, lane = threadIdx.x & 63;
  int node = blockIdx.x * 4 + wv;
  if (node >= N) return;
  int e0 = sptr[node], e1 = sptr[node + 1];
  float sx = 0.f, sy = 0.f, sz = 0.f, sw = 0.f;
  for (int e = e0; e < e1; ++e) {
    int dd = sdst[e];
    float4 xv = ld4h(x_h + (size_t)dd * 256 + lane * 4);
    sx += xv.x; sy += xv.y; sz += xv.z; sw += xv.w;
  }
  float cnt = fmaxf((float)(e1 - e0), 1.0f);
  float4 xm = ((const float4*)(x + (size_t)node * 256))[lane];
  float dx = xm.x - sx / cnt, dy = xm.y - sy / cnt, dz = xm.z - sz / cnt, dw = xm.w - sw / cnt;
  float ss = dx * dx + dy * dy + dz * dz + dw * dw;
  ss += __shfl_xor(ss, 1);  ss += __shfl_xor(ss, 2);  ss += __shfl_xor(ss, 4);
  ss += __shfl_xor(ss, 8);  ss += __shfl_xor(ss, 16); ss += __shfl_xor(ss, 32);
  if (lane == 0) {
    float fv = sqrtf(ss);
    fvar[node] = fv;
    atomicMax(&maxc[0], (unsigned)(e1 - e0));
    atomicMax(&maxc[1], (unsigned)(sp_i[node] - 1));
    atomicMax(&maxc[2], __float_as_uint(fv));
  }
}

// ===================== per-scale hidden h = relu(dens @ Wd1^T + bd1) =====================
__global__ __launch_bounds__(256) void h_kernel(
    const int* __restrict__ sptr, const int* __restrict__ sp_i, const float* __restrict__ fvar,
    const unsigned* __restrict__ maxc, const float* __restrict__ Wd1s,
    const float* __restrict__ bd1s, f16* __restrict__ hbuf, int N)
{
  int id = blockIdx.x * 256 + threadIdx.x;
  if (id >= N * 128) return;
  int node = id >> 7, j = id & 127;
  float dm = (float)maxc[0] + 1e-8f;
  float sm = (float)maxc[1] + 1e-8f;
  float fm = __uint_as_float(maxc[2]) + 1e-8f;
  float d0 = (float)(sptr[node + 1] - sptr[node]) / dm;
  float d1 = (float)(sp_i[node] - 1) / sm;
  float d2 = fvar[node] / fm;
  const float* wr = Wd1s + j * 3;
  float h = fmaxf(wr[0] * d0 + wr[1] * d1 + wr[2] * d2 + bd1s[j], 0.0f);
  hbuf[(size_t)node * 128 + j] = (f16)h;
}

// ===================== fp16 MFMA GEMM:  C[M,N] = A[M,K] @ B[N,K]^T (+bias) =====================
// 128x128 tile, BK=64, 4 waves (2x2 of 64x64), mfma_f32_16x16x32_f16
__global__ __launch_bounds__(256) void gemm_bt_f16(
    const f16* __restrict__ A, int lda,
    const f16* __restrict__ B, int ldb,
    const float* __restrict__ bias,
    void* __restrict__ Cv, int ldc, int K, int Mstore, int outIsF16)
{
  __shared__ f16 As[128 * 64];
  __shared__ f16 Bs[128 * 64];
  const int tid = threadIdx.x;
  const int lane = tid & 63;
  const int w = tid >> 6;
  const int wr = (w >> 1) * 64, wc = (w & 1) * 64;
  const int srow = tid >> 3;            // 0..31
  const int scol = (tid & 7) * 8;       // 0..56 step 8
  const size_t aoff = (size_t)(blockIdx.x * 128 + srow) * lda + scol;
  const size_t boff = (size_t)(blockIdx.y * 128 + srow) * ldb + scol;

  f32x4 acc[4][4] = {};

  for (int kt = 0; kt < K; kt += 64) {
    __syncthreads();
#pragma unroll
    for (int i = 0; i < 4; ++i) {
      f16x8 av = *(const f16x8*)(A + aoff + (size_t)i * 32 * lda + kt);
      *(f16x8*)&As[(i * 32 + srow) * 64 + scol] = av;
      f16x8 bv = *(const f16x8*)(B + boff + (size_t)i * 32 * ldb + kt);
      *(f16x8*)&Bs[(i * 32 + srow) * 64 + scol] = bv;
    }
    __syncthreads();
#pragma unroll
    for (int kq = 0; kq < 2; ++kq) {
      const int krd = kq * 32 + (lane >> 4) * 8;
      f16x8 af[4], bfr[4];
#pragma unroll
      for (int t = 0; t < 4; ++t) {
        af[t]  = *(const f16x8*)&As[(wr + t * 16 + (lane & 15)) * 64 + krd];
        bfr[t] = *(const f16x8*)&Bs[(wc + t * 16 + (lane & 15)) * 64 + krd];
      }
#pragma unroll
      for (int mi = 0; mi < 4; ++mi)
#pragma unroll
        for (int ni = 0; ni < 4; ++ni)
          acc[mi][ni] = __builtin_amdgcn_mfma_f32_16x16x32_f16(af[mi], bfr[ni], acc[mi][ni], 0, 0, 0);
    }
  }

  const int r0 = (lane >> 4) << 2;
  const int c0 = lane & 15;
#pragma unroll
  for (int mi = 0; mi < 4; ++mi) {
#pragma unroll
    for (int ni = 0; ni < 4; ++ni) {
      int col = blockIdx.y * 128 + wc + ni * 16 + c0;
      float bv = bias ? bias[col] : 0.0f;
#pragma unroll
      for (int r = 0; r < 4; ++r) {
        int row = blockIdx.x * 128 + wr + mi * 16 + r0 + r;
        if (row < Mstore) {
          float v = acc[mi][ni][r] + bv;
          if (outIsF16) ((f16*)Cv)[(size_t)row * ldc + col] = (f16)v;
          else          ((float*)Cv)[(size_t)row * ldc + col] = v;
        }
      }
    }
  }
}

// ===================== normalize df rows -> dfn (f16) into node record =====================
__global__ __launch_bounds__(256) void norm_kernel(const float* __restrict__ dfr,
                                                   f16* __restrict__ nrec, int N)
{
  int wv = threadIdx.x >> 6, lane = threadIdx.x & 63;
  int node = blockIdx.x * 4 + wv;
  if (node >= N) return;
  float4 d = ((const float4*)(dfr + (size_t)node * 256))[lane];
  float ss = d.x * d.x + d.y * d.y + d.z * d.z + d.w * d.w;
  ss += __shfl_xor(ss, 1);  ss += __shfl_xor(ss, 2);  ss += __shfl_xor(ss, 4);
  ss += __shfl_xor(ss, 8);  ss += __shfl_xor(ss, 16); ss += __shfl_xor(ss, 32);
  float rn = 1.0f / fmaxf(sqrtf(ss), 1e-8f);
  f16x4 o; o[0] = (f16)(d.x * rn); o[1] = (f16)(d.y * rn); o[2] = (f16)(d.z * rn); o[3] = (f16)(d.w * rn);
  ((f16x4*)(nrec + (size_t)node * 1024 + 768))[lane] = o;
}

// ===================== edge attention: one wave per destination node =====================
// nrec row (per node, f16): [0:256)=q  [256:512)=k  [512:768)=v  [768:1024)=dfn
__global__ __launch_bounds__(256) void edge_attn(
    const f16* __restrict__ nrec, const int2* __restrict__ erec, const int* __restrict__ dptr,
    const float* __restrict__ enc_s, const float* __restrict__ temp_s,
    f16* __restrict__ aggh, int N, int sshift)
{
  int wv = threadIdx.x >> 6, lane = threadIdx.x & 63;
  int node = blockIdx.x * 4 + wv;
  if (node >= N) return;
  const f16* qrow = nrec + (size_t)node * 1024;
  float4 q = ld4h(qrow + lane * 4);
  float4 dfi = ld4h(qrow + 768 + lane * 4);
  float th = temp_s[lane >> 3];
  float m = -INFINITY, z = 0.0f;
  float ax = 0.f, ay = 0.f, az = 0.f, aw = 0.f;
  int e0 = dptr[node], e1 = dptr[node + 1];
  int2 rec = make_int2(0, 0);
  if (e0 < e1) rec = erec[e0];
  for (int e = e0; e < e1; ++e) {
    int src = rec.x;
    unsigned pb = (unsigned)rec.y;
    if (e + 1 < e1) rec = erec[e + 1];
    const f16* srow = nrec + (size_t)src * 1024;
    float4 kv = ld4h(srow + 256 + lane * 4);
    float4 dj = ld4h(srow + 768 + lane * 4);
    float4 vv = ld4h(srow + 512 + lane * 4);
    float qk = q.x * kv.x + q.y * kv.y + q.z * kv.z + q.w * kv.w;
    float ds = dfi.x * dj.x + dfi.y * dj.y + dfi.z * dj.z + dfi.w * dj.w;
    qk += __shfl_xor(qk, 1); ds += __shfl_xor(ds, 1);
    qk += __shfl_xor(qk, 2); ds += __shfl_xor(ds, 2);
    qk += __shfl_xor(qk, 4); ds += __shfl_xor(ds, 4);
    ds += __shfl_xor(ds, 8); ds += __shfl_xor(ds, 16); ds += __shfl_xor(ds, 32);
    unsigned dbin = (pb >> sshift) & 127u;
    unsigned abin = pb >> 21;
    float enc = enc_s[dbin * 16 + abin];
    float sc = (qk / 5.656854249492380195f) / th + enc;
    sc = sc * (1.0f + 0.5f * ds);
    float mn = fmaxf(m, sc);
    float rs = __expf(m - mn);     // 0 on first edge (m = -inf)
    float pp = __expf(sc - mn);
    z = z * rs + pp;
    ax = ax * rs + pp * vv.x; ay = ay * rs + pp * vv.y;
    az = az * rs + pp * vv.z; aw = aw * rs + pp * vv.w;
    m = mn;
  }
  float rz = 1.0f / (z + 1e-16f);
  f16x4 o; o[0] = (f16)(ax * rz); o[1] = (f16)(ay * rz); o[2] = (f16)(az * rz); o[3] = (f16)(aw * rz);
  ((f16x4*)(aggh + (size_t)node * 256))[lane] = o;
}

// ===================== host launcher =====================
extern "C" void kernel_launch(void* const* d_in, const int* in_sizes, int n_in,
                              void* d_out, int out_size, void* d_ws, size_t ws_size,
                              hipStream_t stream)
{
  const float* x      = (const float*)d_in[0];
  const float* coords = (const float*)d_in[1];
  const int*   eidx   = (const int*)  d_in[2];
  const float* Wq   = (const float*)d_in[3];
  const float* Wk   = (const float*)d_in[4];
  const float* Wv   = (const float*)d_in[5];
  const float* Wo   = (const float*)d_in[6];
  const float* bo   = (const float*)d_in[7];
  const float* temp = (const float*)d_in[8];
  const float* dist_emb = (const float*)d_in[9];
  const float* dir_emb  = (const float*)d_in[10];
  const float* Wsp1 = (const float*)d_in[11];
  const float* bsp1 = (const float*)d_in[12];
  const float* Wsp2 = (const float*)d_in[13];
  const float* bsp2 = (const float*)d_in[14];
  const float* Wd1  = (const float*)d_in[15];
  const float* bd1  = (const float*)d_in[16];
  const float* Wd2  = (const float*)d_in[17];
  const float* bd2  = (const float*)d_in[18];
  const float* Wf   = (const float*)d_in[19];
  const float* bf   = (const float*)d_in[20];
  (void)n_in; (void)out_size; (void)ws_size;

  const int N  = in_sizes[0] / 256;
  const int E  = in_sizes[2] / 2;
  const int Mp = ((N + 127) / 128) * 128;

  char* p = (char*)d_ws;
  auto alloc = [&](size_t b) -> void* {
    void* r = (void*)p;
    p += (b + 255) & ~(size_t)255;
    return r;
  };

  f16*   x_h   = (f16*)  alloc((size_t)Mp * 256 * 2);
  f16*   nrec  = (f16*)  alloc((size_t)Mp * 1024 * 2);   // q|k|v|dfn per node (per scale, reused)
  f16*   hbuf  = (f16*)  alloc((size_t)Mp * 128 * 2);
  float* dfr   = (float*)alloc((size_t)Mp * 256 * 4);
  f16*   aggh  = (f16*)  alloc((size_t)Mp * 256 * 2);
  f16*   outsh = (f16*)  alloc((size_t)Mp * 768 * 2);
  f16*   wqkv  = (f16*)  alloc((size_t)3 * 768 * 256 * 2);
  f16*   wo_h  = (f16*)  alloc((size_t)3 * 256 * 256 * 2);
  f16*   wf_h  = (f16*)  alloc((size_t)256 * 768 * 2);
  f16*   wd2h  = (f16*)  alloc((size_t)3 * 256 * 128 * 2);
  float* enc_tab = (float*)alloc((size_t)3 * 1600 * 4);
  int*  dptr = (int*) alloc((size_t)(N + 1) * 4);
  int*  sptr = (int*) alloc((size_t)(N + 1) * 4);
  int2* erec = (int2*)alloc((size_t)E * 8);
  int*  sdst = (int*) alloc((size_t)E * 4);
  float* fvar = (float*)alloc((size_t)N * 4);
  // ---- zeroed-every-call block ----
  char* z0 = p;
  int* deg_i   = (int*)alloc((size_t)N * 4);
  int* indeg_i = (int*)alloc((size_t)N * 4);
  int* fill_d  = (int*)alloc((size_t)N * 4);
  int* fill_s  = (int*)alloc((size_t)N * 4);
  int* sp_i    = (int*)alloc((size_t)N * 4);
  unsigned* maxc = (unsigned*)alloc(4 * 4);
  size_t zbytes = (size_t)(p - z0);
  hipMemsetAsync(z0, 0, zbytes, stream);

  // 1. casts
  cast_kernel<<<2048, 256, 0, stream>>>(x, Wq, Wk, Wv, Wo, Wf, Wd2,
                                        x_h, wqkv, wo_h, wf_h, wd2h, N);
  // 2. enc tables
  enc_kernel<<<(4800 + 255) / 256, 256, 0, stream>>>(dist_emb, dir_emb, Wsp1, bsp1, Wsp2, bsp2, enc_tab);
  // 3. degree histograms
  hist_kernel<<<(E + 255) / 256, 256, 0, stream>>>(eidx, deg_i, indeg_i, E);
  // 4. scans -> CSR offsets
  scan_kernel<<<1, 1024, 0, stream>>>(indeg_i, deg_i, dptr, sptr, N);
  // 5. CSR scatter + edge bins
  scatter_kernel<<<(E + 255) / 256, 256, 0, stream>>>(eidx, coords, dptr, sptr,
                                                      fill_d, fill_s, erec, sdst, E);
  // 6. spatial density
  {
    dim3 g((N + 255) / 256, (N + 2047) / 2048);
    sp_kernel<<<g, 256, 0, stream>>>(coords, sp_i, N);
  }
  // 7. fvar + maxes
  fvar_kernel<<<(N + 3) / 4, 256, 0, stream>>>(x, x_h, sptr, sdst, sp_i, fvar, maxc, N);

  const int mtiles = Mp / 128;
  for (int s = 0; s < 3; ++s) {
    // density MLP
    h_kernel<<<(N * 128 + 255) / 256, 256, 0, stream>>>(sptr, sp_i, fvar, maxc,
                                                        Wd1 + s * 384, bd1 + s * 128, hbuf, N);
    gemm_bt_f16<<<dim3(mtiles, 2), 256, 0, stream>>>(hbuf, 128, wd2h + (size_t)s * 32768, 128,
                                                     bd2 + s * 256, dfr, 256, 128, Mp, 0);
    norm_kernel<<<(N + 3) / 4, 256, 0, stream>>>(dfr, nrec, N);
    // q,k,v
    gemm_bt_f16<<<dim3(mtiles, 6), 256, 0, stream>>>(x_h, 256, wqkv + (size_t)s * 196608, 256,
                                                     nullptr, nrec, 1024, 256, Mp, 1);
    // edge-wise attention + scatter softmax + aggregate
    edge_attn<<<(N + 3) / 4, 256, 0, stream>>>(nrec, erec, dptr, enc_tab + s * 1600,
                                               temp + s * 8, aggh, N, 7 * s);
    // output projection into concat buffer
    gemm_bt_f16<<<dim3(mtiles, 2), 256, 0, stream>>>(aggh, 256, wo_h + (size_t)s * 65536, 256,
                                                     bo + s * 256, outsh + s * 256, 768, 256, Mp, 1);
  }
  // fusion GEMM -> d_out (f32), guard rows < N
  gemm_bt_f16<<<dim3(mtiles, 2), 256, 0, stream>>>(outsh, 768, wf_h, 768,
                                                   bf, d_out, 256, 768, N, 0);
}

// Round 2
// 643.412 us; speedup vs baseline: 1.5415x; 1.5415x over previous
//
#include <hip/hip_runtime.h>

typedef _Float16 f16;
typedef _Float16 f16x4 __attribute__((ext_vector_type(4)));
typedef _Float16 f16x8 __attribute__((ext_vector_type(8)));
typedef float    f32x4 __attribute__((ext_vector_type(4)));

__device__ __forceinline__ float4 ld4h(const f16* p) {
  f16x4 t = *(const f16x4*)p;
  return make_float4((float)t[0], (float)t[1], (float)t[2], (float)t[3]);
}

__device__ __forceinline__ void gld_lds16(const void* g, void* l) {
  __builtin_amdgcn_global_load_lds(
      (const __attribute__((address_space(1))) unsigned*)g,
      (__attribute__((address_space(3))) unsigned*)l, 16, 0, 0);
}

// ===================== pack: f32 -> f16 casts (x + all GEMM weights) =====================
__global__ __launch_bounds__(256) void cast_kernel(
    const float* __restrict__ x, const float* __restrict__ Wq, const float* __restrict__ Wk,
    const float* __restrict__ Wv, const float* __restrict__ Wo, const float* __restrict__ Wf,
    const float* __restrict__ Wd2,
    f16* __restrict__ x_h, f16* __restrict__ wqkv, f16* __restrict__ wo_h,
    f16* __restrict__ wf_h, f16* __restrict__ wd2h, int N)
{
  const int n0 = N * 64;  // x elements in float4 units
  const int total = n0 + 147456 + 49152 + 49152 + 24576;
  for (int i = blockIdx.x * 256 + threadIdx.x; i < total; i += gridDim.x * 256) {
    const float4* sp; f16x4* dp;
    int k = i;
    if (k < n0) { sp = (const float4*)x + k; dp = (f16x4*)x_h + k; }
    else {
      k -= n0;
      if (k < 147456) {  // wqkv: [s][q|k|v][256][256] -> [s][768][256]
        int s = k / 49152, r = k % 49152, m = r / 16384, off = r % 16384;
        const float* w = (m == 0) ? Wq : (m == 1) ? Wk : Wv;
        sp = (const float4*)(w + s * 65536) + off;
        dp = (f16x4*)wqkv + k;
      } else {
        k -= 147456;
        if (k < 49152) { sp = (const float4*)Wo + k; dp = (f16x4*)wo_h + k; }
        else {
          k -= 49152;
          if (k < 49152) { sp = (const float4*)Wf + k; dp = (f16x4*)wf_h + k; }
          else { k -= 49152; sp = (const float4*)Wd2 + k; dp = (f16x4*)wd2h + k; }
        }
      }
    }
    float4 v = *sp;
    f16x4 o; o[0] = (f16)v.x; o[1] = (f16)v.y; o[2] = (f16)v.z; o[3] = (f16)v.w;
    *dp = o;
  }
}

// ===================== enc lookup table: [3][100][16] =====================
__global__ __launch_bounds__(256) void enc_kernel(
    const float* __restrict__ dist_emb, const float* __restrict__ dir_emb,
    const float* __restrict__ Wsp1, const float* __restrict__ bsp1,
    const float* __restrict__ Wsp2, const float* __restrict__ bsp2,
    float* __restrict__ enc_tab)
{
  int id = blockIdx.x * 256 + threadIdx.x;
  if (id >= 3 * 1600) return;
  int s = id / 1600, c = id % 1600, db = c >> 4, ab = c & 15;
  const float* de = dist_emb + (size_t)(s * 100 + db) * 16;
  const float* ae = dir_emb + (size_t)(s * 16 + ab) * 16;
  const float* w1 = Wsp1 + s * 1024;
  const float* b1 = bsp1 + s * 32;
  const float* w2 = Wsp2 + s * 32;
  float enc = bsp2[s];
  for (int j = 0; j < 32; ++j) {
    float a = b1[j];
    const float* wr = w1 + j * 32;
#pragma unroll
    for (int i = 0; i < 16; ++i) a += de[i] * wr[i];
#pragma unroll
    for (int i = 0; i < 16; ++i) a += ae[i] * wr[16 + i];
    enc += fmaxf(a, 0.0f) * w2[j];
  }
  enc_tab[id] = enc;
}

// ===================== degree histograms =====================
__global__ __launch_bounds__(256) void hist_kernel(const int* __restrict__ eidx,
                                                   int* deg_i, int* indeg_i, int E)
{
  int e = blockIdx.x * 256 + threadIdx.x;
  if (e >= E) return;
  atomicAdd(&deg_i[eidx[e]], 1);
  atomicAdd(&indeg_i[eidx[E + e]], 1);
}

// ===================== single-block exclusive scan of both histograms =====================
__global__ __launch_bounds__(1024) void scan_kernel(const int* __restrict__ indeg,
                                                    const int* __restrict__ deg,
                                                    int* dptr, int* sptr, int N)
{
  __shared__ int lds[1024];
  const int tid = threadIdx.x;
  for (int pass = 0; pass < 2; ++pass) {
    const int* in = pass ? deg : indeg;
    int* out = pass ? sptr : dptr;
    int base = tid * 16;
    int loc[16];
    int sum = 0;
#pragma unroll
    for (int j = 0; j < 16; ++j) {
      int v = (base + j < N) ? in[base + j] : 0;
      loc[j] = sum; sum += v;
    }
    lds[tid] = sum;
    __syncthreads();
    for (int off = 1; off < 1024; off <<= 1) {
      int t = (tid >= off) ? lds[tid - off] : 0;
      __syncthreads();
      lds[tid] += t;
      __syncthreads();
    }
    int prev = tid ? lds[tid - 1] : 0;
#pragma unroll
    for (int j = 0; j < 16; ++j)
      if (base + j < N) out[base + j] = prev + loc[j];
    if (tid == 1023) out[N] = lds[1023];
    __syncthreads();
  }
}

// ===================== CSR scatter + per-edge geometry bins =====================
__global__ __launch_bounds__(256) void scatter_kernel(
    const int* __restrict__ eidx, const float* __restrict__ coords,
    const int* __restrict__ dptr, const int* __restrict__ sptr,
    int* fill_d, int* fill_s, int2* __restrict__ erec, int* __restrict__ sdst, int E)
{
  int e = blockIdx.x * 256 + threadIdx.x;
  if (e >= E) return;
  int s = eidx[e], d = eidx[E + e];
  float rx = coords[2 * s] - coords[2 * d];
  float ry = coords[2 * s + 1] - coords[2 * d + 1];
  float dist = sqrtf(rx * rx + ry * ry);
  float ang = atan2f(ry, rx);
  int ab = (int)((ang + 3.14159265358979323846f) / 6.28318530717958647692f * 15.0f);
  ab = ab < 0 ? 0 : (ab > 15 ? 15 : ab);
  int b0 = (int)((dist / 500.0f) * 99.0f);  b0 = b0 < 0 ? 0 : (b0 > 99 ? 99 : b0);
  int b1 = (int)((dist / 1000.0f) * 99.0f); b1 = b1 < 0 ? 0 : (b1 > 99 ? 99 : b1);
  int b2 = (int)((dist / 2000.0f) * 99.0f); b2 = b2 < 0 ? 0 : (b2 > 99 ? 99 : b2);
  unsigned pb = (unsigned)b0 | ((unsigned)b1 << 7) | ((unsigned)b2 << 14) | ((unsigned)ab << 21);
  int pd = dptr[d] + atomicAdd(&fill_d[d], 1);
  erec[pd] = make_int2(s, (int)pb);
  int ps = sptr[s] + atomicAdd(&fill_s[s], 1);
  sdst[ps] = d;
}

// ===================== spatial density: O(N^2) radius count =====================
__global__ __launch_bounds__(256) void sp_kernel(const float* __restrict__ coords,
                                                 int* __restrict__ sp_i, int N)
{
  __shared__ float2 cj[512];
  int j0 = blockIdx.y * 512;
  int jn = N - j0; if (jn > 512) jn = 512;
  for (int j = threadIdx.x; j < jn; j += 256) cj[j] = ((const float2*)coords)[j0 + j];
  __syncthreads();
  int i = blockIdx.x * 256 + threadIdx.x;
  if (i >= N) return;
  float cx = coords[2 * i], cy = coords[2 * i + 1];
  int cnt = 0;
  for (int j = 0; j < jn; ++j) {
    float dx = cx - cj[j].x, dy = cy - cj[j].y;
    float dd = sqrtf(dx * dx + dy * dy);
    cnt += (dd <= 50.0f) ? 1 : 0;
  }
  atomicAdd(&sp_i[i], cnt);
}

// ===================== fvar (local feature variance), NO atomics =====================
__global__ __launch_bounds__(256) void fvar_kernel(
    const float* __restrict__ x, const f16* __restrict__ x_h,
    const int* __restrict__ sptr, const int* __restrict__ sdst,
    float* __restrict__ fvar, int N)
{
  int wv = threadIdx.x >> 6, lane = threadIdx.x & 63;
  int node = blockIdx.x * 4 + wv;
  if (node >= N) return;
  int e0 = sptr[node], e1 = sptr[node + 1];
  float sx = 0.f, sy = 0.f, sz = 0.f, sw = 0.f;
  for (int e = e0; e < e1; ++e) {
    int dd = sdst[e];
    float4 xv = ld4h(x_h + (size_t)dd * 256 + lane * 4);
    sx += xv.x; sy += xv.y; sz += xv.z; sw += xv.w;
  }
  float cnt = fmaxf((float)(e1 - e0), 1.0f);
  float4 xm = ((const float4*)(x + (size_t)node * 256))[lane];
  float dx = xm.x - sx / cnt, dy = xm.y - sy / cnt, dz = xm.z - sz / cnt, dw = xm.w - sw / cnt;
  float ss = dx * dx + dy * dy + dz * dz + dw * dw;
  ss += __shfl_xor(ss, 1);  ss += __shfl_xor(ss, 2);  ss += __shfl_xor(ss, 4);
  ss += __shfl_xor(ss, 8);  ss += __shfl_xor(ss, 16); ss += __shfl_xor(ss, 32);
  if (lane == 0) fvar[node] = sqrtf(ss);
}

// ===================== global maxes: single block, LDS tree, zero atomics =====================
__global__ __launch_bounds__(1024) void maxred_kernel(
    const int* __restrict__ sptr, const int* __restrict__ sp_i,
    const float* __restrict__ fvar, float* __restrict__ maxf, int N)
{
  __shared__ float l0[1024], l1[1024], l2[1024];
  int tid = threadIdx.x;
  float m0 = 0.f, m1 = 0.f, m2 = 0.f;
  for (int i = tid; i < N; i += 1024) {
    m0 = fmaxf(m0, (float)(sptr[i + 1] - sptr[i]));
    m1 = fmaxf(m1, (float)(sp_i[i] - 1));
    m2 = fmaxf(m2, fvar[i]);
  }
  l0[tid] = m0; l1[tid] = m1; l2[tid] = m2;
  __syncthreads();
  for (int off = 512; off > 0; off >>= 1) {
    if (tid < off) {
      l0[tid] = fmaxf(l0[tid], l0[tid + off]);
      l1[tid] = fmaxf(l1[tid], l1[tid + off]);
      l2[tid] = fmaxf(l2[tid], l2[tid + off]);
    }
    __syncthreads();
  }
  if (tid == 0) { maxf[0] = l0[0]; maxf[1] = l1[0]; maxf[2] = l2[0]; }
}

// ===================== per-scale hidden h = relu(dens @ Wd1^T + bd1) =====================
__global__ __launch_bounds__(256) void h_kernel(
    const int* __restrict__ sptr, const int* __restrict__ sp_i, const float* __restrict__ fvar,
    const float* __restrict__ maxf, const float* __restrict__ Wd1s,
    const float* __restrict__ bd1s, f16* __restrict__ hbuf, int N)
{
  int id = blockIdx.x * 256 + threadIdx.x;
  if (id >= N * 128) return;
  int node = id >> 7, j = id & 127;
  float dm = maxf[0] + 1e-8f;
  float sm = maxf[1] + 1e-8f;
  float fm = maxf[2] + 1e-8f;
  float d0 = (float)(sptr[node + 1] - sptr[node]) / dm;
  float d1 = (float)(sp_i[node] - 1) / sm;
  float d2 = fvar[node] / fm;
  const float* wr = Wd1s + j * 3;
  float h = fmaxf(wr[0] * d0 + wr[1] * d1 + wr[2] * d2 + bd1s[j], 0.0f);
  hbuf[(size_t)node * 128 + j] = (f16)h;
}

// ===================== fp16 MFMA GEMM:  C[M,N] = A[M,K] @ B[N,K]^T (+bias) =====================
// 128x128 tile, BK=64, 4 waves (2x2 of 64x64), mfma_f32_16x16x32_f16,
// global_load_lds width-16 staging (LDS dest is linear tid*16 per buffer chunk).
__global__ __launch_bounds__(256) void gemm_bt_f16(
    const f16* __restrict__ A, int lda,
    const f16* __restrict__ B, int ldb,
    const float* __restrict__ bias,
    void* __restrict__ Cv, int ldc, int K, int Mstore, int outIsF16)
{
  __shared__ f16 As[128 * 64];
  __shared__ f16 Bs[128 * 64];
  const int tid = threadIdx.x;
  const int lane = tid & 63;
  const int w = tid >> 6;
  const int wr = (w >> 1) * 64, wc = (w & 1) * 64;
  const int srow = tid >> 3;            // 0..31
  const int scol = (tid & 7) * 8;       // 0..56 step 8
  const f16* Ab = A + (size_t)(blockIdx.x * 128 + srow) * lda + scol;
  const f16* Bb = B + (size_t)(blockIdx.y * 128 + srow) * ldb + scol;
  char* Asl = (char*)As + tid * 16;
  char* Bsl = (char*)Bs + tid * 16;

  f32x4 acc[4][4] = {};

  for (int kt = 0; kt < K; kt += 64) {
    __syncthreads();
#pragma unroll
    for (int i = 0; i < 4; ++i) {
      gld_lds16(Ab + (size_t)i * 32 * lda + kt, Asl + i * 4096);
      gld_lds16(Bb + (size_t)i * 32 * ldb + kt, Bsl + i * 4096);
    }
    __syncthreads();
#pragma unroll
    for (int kq = 0; kq < 2; ++kq) {
      const int krd = kq * 32 + (lane >> 4) * 8;
      f16x8 af[4], bfr[4];
#pragma unroll
      for (int t = 0; t < 4; ++t) {
        af[t]  = *(const f16x8*)&As[(wr + t * 16 + (lane & 15)) * 64 + krd];
        bfr[t] = *(const f16x8*)&Bs[(wc + t * 16 + (lane & 15)) * 64 + krd];
      }
#pragma unroll
      for (int mi = 0; mi < 4; ++mi)
#pragma unroll
        for (int ni = 0; ni < 4; ++ni)
          acc[mi][ni] = __builtin_amdgcn_mfma_f32_16x16x32_f16(af[mi], bfr[ni], acc[mi][ni], 0, 0, 0);
    }
  }

  const int r0 = (lane >> 4) << 2;
  const int c0 = lane & 15;
#pragma unroll
  for (int mi = 0; mi < 4; ++mi) {
#pragma unroll
    for (int ni = 0; ni < 4; ++ni) {
      int col = blockIdx.y * 128 + wc + ni * 16 + c0;
      float bv = bias ? bias[col] : 0.0f;
#pragma unroll
      for (int r = 0; r < 4; ++r) {
        int row = blockIdx.x * 128 + wr + mi * 16 + r0 + r;
        if (row < Mstore) {
          float v = acc[mi][ni][r] + bv;
          if (outIsF16) ((f16*)Cv)[(size_t)row * ldc + col] = (f16)v;
          else          ((float*)Cv)[(size_t)row * ldc + col] = v;
        }
      }
    }
  }
}

// ===================== normalize df rows -> dfn (f16) into node record =====================
__global__ __launch_bounds__(256) void norm_kernel(const float* __restrict__ dfr,
                                                   f16* __restrict__ nrec, int N)
{
  int wv = threadIdx.x >> 6, lane = threadIdx.x & 63;
  int node = blockIdx.x * 4 + wv;
  if (node >= N) return;
  float4 d = ((const float4*)(dfr + (size_t)node * 256))[lane];
  float ss = d.x * d.x + d.y * d.y + d.z * d.z + d.w * d.w;
  ss += __shfl_xor(ss, 1);  ss += __shfl_xor(ss, 2);  ss += __shfl_xor(ss, 4);
  ss += __shfl_xor(ss, 8);  ss += __shfl_xor(ss, 16); ss += __shfl_xor(ss, 32);
  float rn = 1.0f / fmaxf(sqrtf(ss), 1e-8f);
  f16x4 o; o[0] = (f16)(d.x * rn); o[1] = (f16)(d.y * rn); o[2] = (f16)(d.z * rn); o[3] = (f16)(d.w * rn);
  ((f16x4*)(nrec + (size_t)node * 1024 + 768))[lane] = o;
}

// ===================== edge attention: one wave per destination node =====================
// nrec row (per node, f16): [0:256)=q  [256:512)=k  [512:768)=v  [768:1024)=dfn
__global__ __launch_bounds__(256) void edge_attn(
    const f16* __restrict__ nrec, const int2* __restrict__ erec, const int* __restrict__ dptr,
    const float* __restrict__ enc_s, const float* __restrict__ temp_s,
    f16* __restrict__ aggh, int N, int sshift)
{
  int wv = threadIdx.x >> 6, lane = threadIdx.x & 63;
  int node = blockIdx.x * 4 + wv;
  if (node >= N) return;
  const f16* qrow = nrec + (size_t)node * 1024;
  float4 q = ld4h(qrow + lane * 4);
  float4 dfi = ld4h(qrow + 768 + lane * 4);
  float th = temp_s[lane >> 3];
  float m = -INFINITY, z = 0.0f;
  float ax = 0.f, ay = 0.f, az = 0.f, aw = 0.f;
  int e0 = dptr[node], e1 = dptr[node + 1];
  int2 rec = make_int2(0, 0);
  if (e0 < e1) rec = erec[e0];
  for (int e = e0; e < e1; ++e) {
    int src = rec.x;
    unsigned pb = (unsigned)rec.y;
    if (e + 1 < e1) rec = erec[e + 1];
    const f16* srow = nrec + (size_t)src * 1024;
    float4 kv = ld4h(srow + 256 + lane * 4);
    float4 dj = ld4h(srow + 768 + lane * 4);
    float4 vv = ld4h(srow + 512 + lane * 4);
    float qk = q.x * kv.x + q.y * kv.y + q.z * kv.z + q.w * kv.w;
    float ds = dfi.x * dj.x + dfi.y * dj.y + dfi.z * dj.z + dfi.w * dj.w;
    qk += __shfl_xor(qk, 1); ds += __shfl_xor(ds, 1);
    qk += __shfl_xor(qk, 2); ds += __shfl_xor(ds, 2);
    qk += __shfl_xor(qk, 4); ds += __shfl_xor(ds, 4);
    ds += __shfl_xor(ds, 8); ds += __shfl_xor(ds, 16); ds += __shfl_xor(ds, 32);
    unsigned dbin = (pb >> sshift) & 127u;
    unsigned abin = pb >> 21;
    float enc = enc_s[dbin * 16 + abin];
    float sc = (qk / 5.656854249492380195f) / th + enc;
    sc = sc * (1.0f + 0.5f * ds);
    float mn = fmaxf(m, sc);
    float rs = __expf(m - mn);     // 0 on first edge (m = -inf)
    float pp = __expf(sc - mn);
    z = z * rs + pp;
    ax = ax * rs + pp * vv.x; ay = ay * rs + pp * vv.y;
    az = az * rs + pp * vv.z; aw = aw * rs + pp * vv.w;
    m = mn;
  }
  float rz = 1.0f / (z + 1e-16f);
  f16x4 o; o[0] = (f16)(ax * rz); o[1] = (f16)(ay * rz); o[2] = (f16)(az * rz); o[3] = (f16)(aw * rz);
  ((f16x4*)(aggh + (size_t)node * 256))[lane] = o;
}

// ===================== host launcher =====================
extern "C" void kernel_launch(void* const* d_in, const int* in_sizes, int n_in,
                              void* d_out, int out_size, void* d_ws, size_t ws_size,
                              hipStream_t stream)
{
  const float* x      = (const float*)d_in[0];
  const float* coords = (const float*)d_in[1];
  const int*   eidx   = (const int*)  d_in[2];
  const float* Wq   = (const float*)d_in[3];
  const float* Wk   = (const float*)d_in[4];
  const float* Wv   = (const float*)d_in[5];
  const float* Wo   = (const float*)d_in[6];
  const float* bo   = (const float*)d_in[7];
  const float* temp = (const float*)d_in[8];
  const float* dist_emb = (const float*)d_in[9];
  const float* dir_emb  = (const float*)d_in[10];
  const float* Wsp1 = (const float*)d_in[11];
  const float* bsp1 = (const float*)d_in[12];
  const float* Wsp2 = (const float*)d_in[13];
  const float* bsp2 = (const float*)d_in[14];
  const float* Wd1  = (const float*)d_in[15];
  const float* bd1  = (const float*)d_in[16];
  const float* Wd2  = (const float*)d_in[17];
  const float* bd2  = (const float*)d_in[18];
  const float* Wf   = (const float*)d_in[19];
  const float* bf   = (const float*)d_in[20];
  (void)n_in; (void)out_size; (void)ws_size;

  const int N  = in_sizes[0] / 256;
  const int E  = in_sizes[2] / 2;
  const int Mp = ((N + 127) / 128) * 128;

  char* p = (char*)d_ws;
  auto alloc = [&](size_t b) -> void* {
    void* r = (void*)p;
    p += (b + 255) & ~(size_t)255;
    return r;
  };

  f16*   x_h   = (f16*)  alloc((size_t)Mp * 256 * 2);
  f16*   nrec  = (f16*)  alloc((size_t)Mp * 1024 * 2);   // q|k|v|dfn per node (per scale, reused)
  f16*   hbuf  = (f16*)  alloc((size_t)Mp * 128 * 2);
  float* dfr   = (float*)alloc((size_t)Mp * 256 * 4);
  f16*   aggh  = (f16*)  alloc((size_t)Mp * 256 * 2);
  f16*   outsh = (f16*)  alloc((size_t)Mp * 768 * 2);
  f16*   wqkv  = (f16*)  alloc((size_t)3 * 768 * 256 * 2);
  f16*   wo_h  = (f16*)  alloc((size_t)3 * 256 * 256 * 2);
  f16*   wf_h  = (f16*)  alloc((size_t)256 * 768 * 2);
  f16*   wd2h  = (f16*)  alloc((size_t)3 * 256 * 128 * 2);
  float* enc_tab = (float*)alloc((size_t)3 * 1600 * 4);
  int*  dptr = (int*) alloc((size_t)(N + 1) * 4);
  int*  sptr = (int*) alloc((size_t)(N + 1) * 4);
  int2* erec = (int2*)alloc((size_t)E * 8);
  int*  sdst = (int*) alloc((size_t)E * 4);
  float* fvar = (float*)alloc((size_t)N * 4);
  float* maxf = (float*)alloc(4 * 4);
  // ---- zeroed-every-call block ----
  char* z0 = p;
  int* deg_i   = (int*)alloc((size_t)N * 4);
  int* indeg_i = (int*)alloc((size_t)N * 4);
  int* fill_d  = (int*)alloc((size_t)N * 4);
  int* fill_s  = (int*)alloc((size_t)N * 4);
  int* sp_i    = (int*)alloc((size_t)N * 4);
  size_t zbytes = (size_t)(p - z0);
  hipMemsetAsync(z0, 0, zbytes, stream);

  // 1. casts
  cast_kernel<<<2048, 256, 0, stream>>>(x, Wq, Wk, Wv, Wo, Wf, Wd2,
                                        x_h, wqkv, wo_h, wf_h, wd2h, N);
  // 2. enc tables
  enc_kernel<<<(4800 + 255) / 256, 256, 0, stream>>>(dist_emb, dir_emb, Wsp1, bsp1, Wsp2, bsp2, enc_tab);
  // 3. degree histograms
  hist_kernel<<<(E + 255) / 256, 256, 0, stream>>>(eidx, deg_i, indeg_i, E);
  // 4. scans -> CSR offsets
  scan_kernel<<<1, 1024, 0, stream>>>(indeg_i, deg_i, dptr, sptr, N);
  // 5. CSR scatter + edge bins
  scatter_kernel<<<(E + 255) / 256, 256, 0, stream>>>(eidx, coords, dptr, sptr,
                                                      fill_d, fill_s, erec, sdst, E);
  // 6. spatial density (512-wide j-chunks -> 800 blocks for occupancy)
  {
    dim3 g((N + 255) / 256, (N + 511) / 512);
    sp_kernel<<<g, 256, 0, stream>>>(coords, sp_i, N);
  }
  // 7. fvar (no atomics)
  fvar_kernel<<<(N + 3) / 4, 256, 0, stream>>>(x, x_h, sptr, sdst, fvar, N);
  // 8. maxes via single-block tree reduction
  maxred_kernel<<<1, 1024, 0, stream>>>(sptr, sp_i, fvar, maxf, N);

  const int mtiles = Mp / 128;
  for (int s = 0; s < 3; ++s) {
    // density MLP
    h_kernel<<<(N * 128 + 255) / 256, 256, 0, stream>>>(sptr, sp_i, fvar, maxf,
                                                        Wd1 + s * 384, bd1 + s * 128, hbuf, N);
    gemm_bt_f16<<<dim3(mtiles, 2), 256, 0, stream>>>(hbuf, 128, wd2h + (size_t)s * 32768, 128,
                                                     bd2 + s * 256, dfr, 256, 128, Mp, 0);
    norm_kernel<<<(N + 3) / 4, 256, 0, stream>>>(dfr, nrec, N);
    // q,k,v
    gemm_bt_f16<<<dim3(mtiles, 6), 256, 0, stream>>>(x_h, 256, wqkv + (size_t)s * 196608, 256,
                                                     nullptr, nrec, 1024, 256, Mp, 1);
    // edge-wise attention + scatter softmax + aggregate
    edge_attn<<<(N + 3) / 4, 256, 0, stream>>>(nrec, erec, dptr, enc_tab + s * 1600,
                                               temp + s * 8, aggh, N, 7 * s);
    // output projection into concat buffer
    gemm_bt_f16<<<dim3(mtiles, 2), 256, 0, stream>>>(aggh, 256, wo_h + (size_t)s * 65536, 256,
                                                     bo + s * 256, outsh + s * 256, 768, 256, Mp, 1);
  }
  // fusion GEMM -> d_out (f32), guard rows < N
  gemm_bt_f16<<<dim3(mtiles, 2), 256, 0, stream>>>(outsh, 768, wf_h, 768,
                                                   bf, d_out, 256, 768, N, 0);
}

// Round 3
// 596.795 us; speedup vs baseline: 1.6619x; 1.0781x over previous
//
#include <hip/hip_runtime.h>

typedef _Float16 f16;
typedef _Float16 f16x4 __attribute__((ext_vector_type(4)));
typedef _Float16 f16x8 __attribute__((ext_vector_type(8)));
typedef float    f32x4 __attribute__((ext_vector_type(4)));
typedef float    fv2   __attribute__((ext_vector_type(2)));

__device__ __forceinline__ float4 ld4h(const f16* p) {
  f16x4 t = *(const f16x4*)p;
  return make_float4((float)t[0], (float)t[1], (float)t[2], (float)t[3]);
}

__device__ __forceinline__ float4 dec_fp8x4(unsigned u) {
  fv2 lo = __builtin_amdgcn_cvt_pk_f32_fp8(u, false);
  fv2 hi = __builtin_amdgcn_cvt_pk_f32_fp8(u, true);
  return make_float4(lo[0], lo[1], hi[0], hi[1]);
}

__device__ __forceinline__ unsigned enc_fp8x4(float a, float b, float c, float d) {
  unsigned v = 0;
  v = __builtin_amdgcn_cvt_pk_fp8_f32(a, b, v, false);
  v = __builtin_amdgcn_cvt_pk_fp8_f32(c, d, v, true);
  return v;
}

__device__ __forceinline__ void gld_lds16(const void* g, void* l) {
  __builtin_amdgcn_global_load_lds(
      (const __attribute__((address_space(1))) unsigned*)g,
      (__attribute__((address_space(3))) unsigned*)l, 16, 0, 0);
}

// ===================== pack: f32 -> f16/fp8 casts (x + all GEMM weights) =====================
// wqvk layout per scale: rows [0:256)=q, [256:512)=v, [512:768)=k  (k tiles feed fp8 output)
__global__ __launch_bounds__(256) void cast_kernel(
    const float* __restrict__ x, const float* __restrict__ Wq, const float* __restrict__ Wk,
    const float* __restrict__ Wv, const float* __restrict__ Wo, const float* __restrict__ Wf,
    const float* __restrict__ Wd2,
    f16* __restrict__ x_h, unsigned* __restrict__ x8, f16* __restrict__ wqvk,
    f16* __restrict__ wo_h, f16* __restrict__ wf_h, f16* __restrict__ wd2h, int N)
{
  const int n0 = N * 64;  // x elements in float4 units
  const int total = n0 + 147456 + 49152 + 49152 + 24576;
  for (int i = blockIdx.x * 256 + threadIdx.x; i < total; i += gridDim.x * 256) {
    int k = i;
    if (k < n0) {
      float4 v = ((const float4*)x)[k];
      f16x4 o; o[0] = (f16)v.x; o[1] = (f16)v.y; o[2] = (f16)v.z; o[3] = (f16)v.w;
      ((f16x4*)x_h)[k] = o;
      x8[k] = enc_fp8x4(v.x, v.y, v.z, v.w);
      continue;
    }
    const float4* sp; f16x4* dp;
    k -= n0;
    if (k < 147456) {  // q|v|k reorg
      int s = k / 49152, r = k % 49152, m = r / 16384, off = r % 16384;
      const float* w = (m == 0) ? Wq : (m == 1) ? Wk : Wv;
      int dblk = (m == 0) ? 0 : (m == 1) ? 32768 : 16384;
      sp = (const float4*)(w + s * 65536) + off;
      dp = (f16x4*)wqvk + s * 49152 + dblk + off;
    } else {
      k -= 147456;
      if (k < 49152) { sp = (const float4*)Wo + k; dp = (f16x4*)wo_h + k; }
      else {
        k -= 49152;
        if (k < 49152) { sp = (const float4*)Wf + k; dp = (f16x4*)wf_h + k; }
        else { k -= 49152; sp = (const float4*)Wd2 + k; dp = (f16x4*)wd2h + k; }
      }
    }
    float4 v = *sp;
    f16x4 o; o[0] = (f16)v.x; o[1] = (f16)v.y; o[2] = (f16)v.z; o[3] = (f16)v.w;
    *dp = o;
  }
}

// ===================== enc lookup table: [3][100][16] =====================
__global__ __launch_bounds__(256) void enc_kernel(
    const float* __restrict__ dist_emb, const float* __restrict__ dir_emb,
    const float* __restrict__ Wsp1, const float* __restrict__ bsp1,
    const float* __restrict__ Wsp2, const float* __restrict__ bsp2,
    float* __restrict__ enc_tab)
{
  int id = blockIdx.x * 256 + threadIdx.x;
  if (id >= 3 * 1600) return;
  int s = id / 1600, c = id % 1600, db = c >> 4, ab = c & 15;
  const float* de = dist_emb + (size_t)(s * 100 + db) * 16;
  const float* ae = dir_emb + (size_t)(s * 16 + ab) * 16;
  const float* w1 = Wsp1 + s * 1024;
  const float* b1 = bsp1 + s * 32;
  const float* w2 = Wsp2 + s * 32;
  float enc = bsp2[s];
  for (int j = 0; j < 32; ++j) {
    float a = b1[j];
    const float* wr = w1 + j * 32;
#pragma unroll
    for (int i = 0; i < 16; ++i) a += de[i] * wr[i];
#pragma unroll
    for (int i = 0; i < 16; ++i) a += ae[i] * wr[16 + i];
    enc += fmaxf(a, 0.0f) * w2[j];
  }
  enc_tab[id] = enc;
}

// ===================== degree histograms =====================
__global__ __launch_bounds__(256) void hist_kernel(const int* __restrict__ eidx,
                                                   int* deg_i, int* indeg_i, int E)
{
  int e = blockIdx.x * 256 + threadIdx.x;
  if (e >= E) return;
  atomicAdd(&deg_i[eidx[e]], 1);
  atomicAdd(&indeg_i[eidx[E + e]], 1);
}

// ===================== single-block exclusive scan of both histograms =====================
__global__ __launch_bounds__(1024) void scan_kernel(const int* __restrict__ indeg,
                                                    const int* __restrict__ deg,
                                                    int* dptr, int* sptr, int N)
{
  __shared__ int lds[1024];
  const int tid = threadIdx.x;
  for (int pass = 0; pass < 2; ++pass) {
    const int* in = pass ? deg : indeg;
    int* out = pass ? sptr : dptr;
    int base = tid * 16;
    int loc[16];
    int sum = 0;
#pragma unroll
    for (int j = 0; j < 16; ++j) {
      int v = (base + j < N) ? in[base + j] : 0;
      loc[j] = sum; sum += v;
    }
    lds[tid] = sum;
    __syncthreads();
    for (int off = 1; off < 1024; off <<= 1) {
      int t = (tid >= off) ? lds[tid - off] : 0;
      __syncthreads();
      lds[tid] += t;
      __syncthreads();
    }
    int prev = tid ? lds[tid - 1] : 0;
#pragma unroll
    for (int j = 0; j < 16; ++j)
      if (base + j < N) out[base + j] = prev + loc[j];
    if (tid == 1023) out[N] = lds[1023];
    __syncthreads();
  }
}

// ===================== CSR scatter + per-edge geometry bins =====================
__global__ __launch_bounds__(256) void scatter_kernel(
    const int* __restrict__ eidx, const float* __restrict__ coords,
    const int* __restrict__ dptr, const int* __restrict__ sptr,
    int* fill_d, int* fill_s, int2* __restrict__ erec, int* __restrict__ sdst, int E)
{
  int e = blockIdx.x * 256 + threadIdx.x;
  if (e >= E) return;
  int s = eidx[e], d = eidx[E + e];
  float rx = coords[2 * s] - coords[2 * d];
  float ry = coords[2 * s + 1] - coords[2 * d + 1];
  float dist = sqrtf(rx * rx + ry * ry);
  float ang = atan2f(ry, rx);
  int ab = (int)((ang + 3.14159265358979323846f) / 6.28318530717958647692f * 15.0f);
  ab = ab < 0 ? 0 : (ab > 15 ? 15 : ab);
  int b0 = (int)((dist / 500.0f) * 99.0f);  b0 = b0 < 0 ? 0 : (b0 > 99 ? 99 : b0);
  int b1 = (int)((dist / 1000.0f) * 99.0f); b1 = b1 < 0 ? 0 : (b1 > 99 ? 99 : b1);
  int b2 = (int)((dist / 2000.0f) * 99.0f); b2 = b2 < 0 ? 0 : (b2 > 99 ? 99 : b2);
  unsigned pb = (unsigned)b0 | ((unsigned)b1 << 7) | ((unsigned)b2 << 14) | ((unsigned)ab << 21);
  int pd = dptr[d] + atomicAdd(&fill_d[d], 1);
  erec[pd] = make_int2(s, (int)pb);
  int ps = sptr[s] + atomicAdd(&fill_s[s], 1);
  sdst[ps] = d;
}

// ===================== spatial density: O(N^2) radius count =====================
__global__ __launch_bounds__(256) void sp_kernel(const float* __restrict__ coords,
                                                 int* __restrict__ sp_i, int N)
{
  __shared__ float2 cj[512];
  int j0 = blockIdx.y * 512;
  int jn = N - j0; if (jn > 512) jn = 512;
  for (int j = threadIdx.x; j < jn; j += 256) cj[j] = ((const float2*)coords)[j0 + j];
  __syncthreads();
  int i = blockIdx.x * 256 + threadIdx.x;
  if (i >= N) return;
  float cx = coords[2 * i], cy = coords[2 * i + 1];
  int cnt = 0;
  for (int j = 0; j < jn; ++j) {
    float dx = cx - cj[j].x, dy = cy - cj[j].y;
    float dd = sqrtf(dx * dx + dy * dy);
    cnt += (dd <= 50.0f) ? 1 : 0;
  }
  atomicAdd(&sp_i[i], cnt);
}

// ===================== fvar (local feature variance), fp8 gathers, no atomics =====================
__global__ __launch_bounds__(256) void fvar_kernel(
    const float* __restrict__ x, const unsigned* __restrict__ x8,
    const int* __restrict__ sptr, const int* __restrict__ sdst,
    float* __restrict__ fvar, int N)
{
  int wv = threadIdx.x >> 6, lane = threadIdx.x & 63;
  int node = blockIdx.x * 4 + wv;
  if (node >= N) return;
  int e0 = sptr[node], e1 = sptr[node + 1];
  float sx = 0.f, sy = 0.f, sz = 0.f, sw = 0.f;
  for (int e = e0; e < e1; e += 2) {
    int d0 = __builtin_amdgcn_readfirstlane(sdst[e]);
    int d1 = __builtin_amdgcn_readfirstlane(sdst[(e + 1 < e1) ? e + 1 : e]);
    float w1 = (e + 1 < e1) ? 1.0f : 0.0f;
    float4 a = dec_fp8x4(x8[d0 * 64 + lane]);
    float4 b = dec_fp8x4(x8[d1 * 64 + lane]);
    sx += a.x + w1 * b.x; sy += a.y + w1 * b.y;
    sz += a.z + w1 * b.z; sw += a.w + w1 * b.w;
  }
  float cnt = fmaxf((float)(e1 - e0), 1.0f);
  float4 xm = ((const float4*)(x + (size_t)node * 256))[lane];
  float dx = xm.x - sx / cnt, dy = xm.y - sy / cnt, dz = xm.z - sz / cnt, dw = xm.w - sw / cnt;
  float ss = dx * dx + dy * dy + dz * dz + dw * dw;
  ss += __shfl_xor(ss, 1);  ss += __shfl_xor(ss, 2);  ss += __shfl_xor(ss, 4);
  ss += __shfl_xor(ss, 8);  ss += __shfl_xor(ss, 16); ss += __shfl_xor(ss, 32);
  if (lane == 0) fvar[node] = sqrtf(ss);
}

// ===================== global maxes: single block, LDS tree, zero atomics =====================
__global__ __launch_bounds__(1024) void maxred_kernel(
    const int* __restrict__ sptr, const int* __restrict__ sp_i,
    const float* __restrict__ fvar, float* __restrict__ maxf, int N)
{
  __shared__ float l0[1024], l1[1024], l2[1024];
  int tid = threadIdx.x;
  float m0 = 0.f, m1 = 0.f, m2 = 0.f;
  for (int i = tid; i < N; i += 1024) {
    m0 = fmaxf(m0, (float)(sptr[i + 1] - sptr[i]));
    m1 = fmaxf(m1, (float)(sp_i[i] - 1));
    m2 = fmaxf(m2, fvar[i]);
  }
  l0[tid] = m0; l1[tid] = m1; l2[tid] = m2;
  __syncthreads();
  for (int off = 512; off > 0; off >>= 1) {
    if (tid < off) {
      l0[tid] = fmaxf(l0[tid], l0[tid + off]);
      l1[tid] = fmaxf(l1[tid], l1[tid + off]);
      l2[tid] = fmaxf(l2[tid], l2[tid + off]);
    }
    __syncthreads();
  }
  if (tid == 0) { maxf[0] = l0[0]; maxf[1] = l1[0]; maxf[2] = l2[0]; }
}

// ===================== per-scale hidden h = relu(dens @ Wd1^T + bd1) =====================
__global__ __launch_bounds__(256) void h_kernel(
    const int* __restrict__ sptr, const int* __restrict__ sp_i, const float* __restrict__ fvar,
    const float* __restrict__ maxf, const float* __restrict__ Wd1s,
    const float* __restrict__ bd1s, f16* __restrict__ hbuf, int N)
{
  int id = blockIdx.x * 256 + threadIdx.x;
  if (id >= N * 128) return;
  int node = id >> 7, j = id & 127;
  float dm = maxf[0] + 1e-8f;
  float sm = maxf[1] + 1e-8f;
  float fm = maxf[2] + 1e-8f;
  float d0 = (float)(sptr[node + 1] - sptr[node]) / dm;
  float d1 = (float)(sp_i[node] - 1) / sm;
  float d2 = fvar[node] / fm;
  const float* wr = Wd1s + j * 3;
  float h = fmaxf(wr[0] * d0 + wr[1] * d1 + wr[2] * d2 + bd1s[j], 0.0f);
  hbuf[(size_t)node * 128 + j] = (f16)h;
}

// ===================== fp16 MFMA GEMM with split output =====================
// C[M,N] = A[M,K] @ B[N,K]^T (+bias); y-tiles >= ysplit write fp8 to Cv2 (rebased cols).
__global__ __launch_bounds__(256) void gemm_bt_f16(
    const f16* __restrict__ A, int lda,
    const f16* __restrict__ B, int ldb,
    const float* __restrict__ bias,
    void* __restrict__ Cv, int ldc, int K, int Mstore, int outMode,
    unsigned char* __restrict__ Cv2, int ldc2, int ysplit)
{
  __shared__ f16 As[128 * 64];
  __shared__ f16 Bs[128 * 64];
  const int tid = threadIdx.x;
  const int lane = tid & 63;
  const int w = tid >> 6;
  const int wr = (w >> 1) * 64, wc = (w & 1) * 64;
  const int srow = tid >> 3;
  const int scol = (tid & 7) * 8;
  const f16* Ab = A + (size_t)(blockIdx.x * 128 + srow) * lda + scol;
  const f16* Bb = B + (size_t)(blockIdx.y * 128 + srow) * ldb + scol;
  char* Asl = (char*)As + tid * 16;
  char* Bsl = (char*)Bs + tid * 16;

  f32x4 acc[4][4] = {};

  for (int kt = 0; kt < K; kt += 64) {
    __syncthreads();
#pragma unroll
    for (int i = 0; i < 4; ++i) {
      gld_lds16(Ab + (size_t)i * 32 * lda + kt, Asl + i * 4096);
      gld_lds16(Bb + (size_t)i * 32 * ldb + kt, Bsl + i * 4096);
    }
    __syncthreads();
#pragma unroll
    for (int kq = 0; kq < 2; ++kq) {
      const int krd = kq * 32 + (lane >> 4) * 8;
      f16x8 af[4], bfr[4];
#pragma unroll
      for (int t = 0; t < 4; ++t) {
        af[t]  = *(const f16x8*)&As[(wr + t * 16 + (lane & 15)) * 64 + krd];
        bfr[t] = *(const f16x8*)&Bs[(wc + t * 16 + (lane & 15)) * 64 + krd];
      }
#pragma unroll
      for (int mi = 0; mi < 4; ++mi)
#pragma unroll
        for (int ni = 0; ni < 4; ++ni)
          acc[mi][ni] = __builtin_amdgcn_mfma_f32_16x16x32_f16(af[mi], bfr[ni], acc[mi][ni], 0, 0, 0);
    }
  }

  const int r0 = (lane >> 4) << 2;
  const int c0 = lane & 15;
  const bool f8p = ((int)blockIdx.y >= ysplit);
  const int cbase = f8p ? ((int)blockIdx.y - ysplit) * 128 : (int)blockIdx.y * 128;
#pragma unroll
  for (int mi = 0; mi < 4; ++mi) {
#pragma unroll
    for (int ni = 0; ni < 4; ++ni) {
      int col = cbase + wc + ni * 16 + c0;
      float bv = (!f8p && bias) ? bias[col] : 0.0f;
#pragma unroll
      for (int r = 0; r < 4; ++r) {
        int row = blockIdx.x * 128 + wr + mi * 16 + r0 + r;
        if (row < Mstore) {
          float v = acc[mi][ni][r] + bv;
          if (f8p) {
            unsigned pk = __builtin_amdgcn_cvt_pk_fp8_f32(v, v, 0u, false);
            Cv2[(size_t)row * ldc2 + col] = (unsigned char)(pk & 0xffu);
          } else if (outMode == 1) {
            ((f16*)Cv)[(size_t)row * ldc + col] = (f16)v;
          } else {
            ((float*)Cv)[(size_t)row * ldc + col] = v;
          }
        }
      }
    }
  }
}

// ===================== normalize df rows -> dfn (fp8) =====================
__global__ __launch_bounds__(256) void norm_kernel(const float* __restrict__ dfr,
                                                   unsigned* __restrict__ drec8, int N)
{
  int wv = threadIdx.x >> 6, lane = threadIdx.x & 63;
  int node = blockIdx.x * 4 + wv;
  if (node >= N) return;
  float4 d = ((const float4*)(dfr + (size_t)node * 256))[lane];
  float ss = d.x * d.x + d.y * d.y + d.z * d.z + d.w * d.w;
  ss += __shfl_xor(ss, 1);  ss += __shfl_xor(ss, 2);  ss += __shfl_xor(ss, 4);
  ss += __shfl_xor(ss, 8);  ss += __shfl_xor(ss, 16); ss += __shfl_xor(ss, 32);
  float rn = 1.0f / fmaxf(sqrtf(ss), 1e-8f);
  drec8[node * 64 + lane] = enc_fp8x4(d.x * rn, d.y * rn, d.z * rn, d.w * rn);
}

// ===================== edge attention: one wave per destination node =====================
// nrec row (per node, f16, 512): [0:256)=q [256:512)=v ; krec8/drec8: fp8 256B rows
__global__ __launch_bounds__(256) void edge_attn(
    const f16* __restrict__ nrec, const unsigned* __restrict__ krec8,
    const unsigned* __restrict__ drec8, const int2* __restrict__ erec,
    const int* __restrict__ dptr, const float* __restrict__ enc_s,
    const float* __restrict__ temp_s, f16* __restrict__ aggh, int N, int sshift)
{
  int wv = threadIdx.x >> 6, lane = threadIdx.x & 63;
  int node = blockIdx.x * 4 + wv;
  if (node >= N) return;
  float4 q = ld4h(nrec + (size_t)node * 512 + lane * 4);
  float4 dfi = dec_fp8x4(drec8[node * 64 + lane]);
  float th = temp_s[lane >> 3];
  float m = -INFINITY, z = 0.0f;
  float ax = 0.f, ay = 0.f, az = 0.f, aw = 0.f;
  int e0 = dptr[node], e1 = dptr[node + 1];
  if (e0 < e1) {
    int2 r0 = erec[e0];
    int2 r1 = erec[(e0 + 1 < e1) ? e0 + 1 : e0];
    for (int e = e0; e < e1; e += 2) {
      int s0 = __builtin_amdgcn_readfirstlane(r0.x);
      unsigned pb0 = (unsigned)__builtin_amdgcn_readfirstlane(r0.y);
      int s1 = __builtin_amdgcn_readfirstlane(r1.x);
      unsigned pb1 = (unsigned)__builtin_amdgcn_readfirstlane(r1.y);
      // prefetch next pair's records
      int en0 = (e + 2 < e1) ? e + 2 : e1 - 1;
      int en1 = (e + 3 < e1) ? e + 3 : e1 - 1;
      r0 = erec[en0]; r1 = erec[en1];
      // gathers for both edges (issued before any reduction)
      unsigned ku0 = krec8[s0 * 64 + lane];
      unsigned du0 = drec8[s0 * 64 + lane];
      float4 v0 = ld4h(nrec + (size_t)s0 * 512 + 256 + lane * 4);
      unsigned ku1 = krec8[s1 * 64 + lane];
      unsigned du1 = drec8[s1 * 64 + lane];
      float4 v1 = ld4h(nrec + (size_t)s1 * 512 + 256 + lane * 4);
      float4 k0 = dec_fp8x4(ku0), d0 = dec_fp8x4(du0);
      float4 k1 = dec_fp8x4(ku1), d1 = dec_fp8x4(du1);
      float qk0 = q.x * k0.x + q.y * k0.y + q.z * k0.z + q.w * k0.w;
      float ds0 = dfi.x * d0.x + dfi.y * d0.y + dfi.z * d0.z + dfi.w * d0.w;
      float qk1 = q.x * k1.x + q.y * k1.y + q.z * k1.z + q.w * k1.w;
      float ds1 = dfi.x * d1.x + dfi.y * d1.y + dfi.z * d1.z + dfi.w * d1.w;
      // 4 independent reduce chains
      qk0 += __shfl_xor(qk0, 1); qk1 += __shfl_xor(qk1, 1);
      ds0 += __shfl_xor(ds0, 1); ds1 += __shfl_xor(ds1, 1);
      qk0 += __shfl_xor(qk0, 2); qk1 += __shfl_xor(qk1, 2);
      ds0 += __shfl_xor(ds0, 2); ds1 += __shfl_xor(ds1, 2);
      qk0 += __shfl_xor(qk0, 4); qk1 += __shfl_xor(qk1, 4);
      ds0 += __shfl_xor(ds0, 4); ds1 += __shfl_xor(ds1, 4);
      ds0 += __shfl_xor(ds0, 8); ds1 += __shfl_xor(ds1, 8);
      ds0 += __shfl_xor(ds0, 16); ds1 += __shfl_xor(ds1, 16);
      ds0 += __shfl_xor(ds0, 32); ds1 += __shfl_xor(ds1, 32);
      float enc0 = enc_s[((pb0 >> sshift) & 127u) * 16 + (pb0 >> 21)];
      float enc1 = enc_s[((pb1 >> sshift) & 127u) * 16 + (pb1 >> 21)];
      float sc0 = (qk0 * 0.17677669529663687f / th + enc0) * (1.0f + 0.5f * ds0);
      float sc1 = (qk1 * 0.17677669529663687f / th + enc1) * (1.0f + 0.5f * ds1);
      if (e + 1 >= e1) sc1 = -1e30f;  // odd tail: edge1 is a duplicate, zero its weight
      float mn = fmaxf(m, fmaxf(sc0, sc1));
      float rs = __expf(m - mn);
      float p0 = __expf(sc0 - mn);
      float p1 = __expf(sc1 - mn);
      z = z * rs + p0 + p1;
      ax = ax * rs + p0 * v0.x + p1 * v1.x;
      ay = ay * rs + p0 * v0.y + p1 * v1.y;
      az = az * rs + p0 * v0.z + p1 * v1.z;
      aw = aw * rs + p0 * v0.w + p1 * v1.w;
      m = mn;
    }
  }
  float rz = 1.0f / (z + 1e-16f);
  f16x4 o; o[0] = (f16)(ax * rz); o[1] = (f16)(ay * rz); o[2] = (f16)(az * rz); o[3] = (f16)(aw * rz);
  ((f16x4*)(aggh + (size_t)node * 256))[lane] = o;
}

// ===================== host launcher =====================
extern "C" void kernel_launch(void* const* d_in, const int* in_sizes, int n_in,
                              void* d_out, int out_size, void* d_ws, size_t ws_size,
                              hipStream_t stream)
{
  const float* x      = (const float*)d_in[0];
  const float* coords = (const float*)d_in[1];
  const int*   eidx   = (const int*)  d_in[2];
  const float* Wq   = (const float*)d_in[3];
  const float* Wk   = (const float*)d_in[4];
  const float* Wv   = (const float*)d_in[5];
  const float* Wo   = (const float*)d_in[6];
  const float* bo   = (const float*)d_in[7];
  const float* temp = (const float*)d_in[8];
  const float* dist_emb = (const float*)d_in[9];
  const float* dir_emb  = (const float*)d_in[10];
  const float* Wsp1 = (const float*)d_in[11];
  const float* bsp1 = (const float*)d_in[12];
  const float* Wsp2 = (const float*)d_in[13];
  const float* bsp2 = (const float*)d_in[14];
  const float* Wd1  = (const float*)d_in[15];
  const float* bd1  = (const float*)d_in[16];
  const float* Wd2  = (const float*)d_in[17];
  const float* bd2  = (const float*)d_in[18];
  const float* Wf   = (const float*)d_in[19];
  const float* bf   = (const float*)d_in[20];
  (void)n_in; (void)out_size; (void)ws_size;

  const int N  = in_sizes[0] / 256;
  const int E  = in_sizes[2] / 2;
  const int Mp = ((N + 127) / 128) * 128;

  char* p = (char*)d_ws;
  auto alloc = [&](size_t b) -> void* {
    void* r = (void*)p;
    p += (b + 255) & ~(size_t)255;
    return r;
  };

  f16*      x_h   = (f16*)     alloc((size_t)Mp * 256 * 2);
  unsigned* x8    = (unsigned*)alloc((size_t)Mp * 256);
  f16*      nrec  = (f16*)     alloc((size_t)Mp * 512 * 2);   // q|v per node (per scale, reused)
  unsigned* krec8 = (unsigned*)alloc((size_t)Mp * 256);
  unsigned* drec8 = (unsigned*)alloc((size_t)Mp * 256);
  f16*      hbuf  = (f16*)     alloc((size_t)Mp * 128 * 2);
  float*    dfr   = (float*)   alloc((size_t)Mp * 256 * 4);
  f16*      aggh  = (f16*)     alloc((size_t)Mp * 256 * 2);
  f16*      outsh = (f16*)     alloc((size_t)Mp * 768 * 2);
  f16*      wqvk  = (f16*)     alloc((size_t)3 * 768 * 256 * 2);
  f16*      wo_h  = (f16*)     alloc((size_t)3 * 256 * 256 * 2);
  f16*      wf_h  = (f16*)     alloc((size_t)256 * 768 * 2);
  f16*      wd2h  = (f16*)     alloc((size_t)3 * 256 * 128 * 2);
  float*    enc_tab = (float*) alloc((size_t)3 * 1600 * 4);
  int*  dptr = (int*) alloc((size_t)(N + 1) * 4);
  int*  sptr = (int*) alloc((size_t)(N + 1) * 4);
  int2* erec = (int2*)alloc((size_t)E * 8);
  int*  sdst = (int*) alloc((size_t)E * 4);
  float* fvar = (float*)alloc((size_t)N * 4);
  float* maxf = (float*)alloc(4 * 4);
  // ---- zeroed-every-call block ----
  char* z0 = p;
  int* deg_i   = (int*)alloc((size_t)N * 4);
  int* indeg_i = (int*)alloc((size_t)N * 4);
  int* fill_d  = (int*)alloc((size_t)N * 4);
  int* fill_s  = (int*)alloc((size_t)N * 4);
  int* sp_i    = (int*)alloc((size_t)N * 4);
  size_t zbytes = (size_t)(p - z0);
  hipMemsetAsync(z0, 0, zbytes, stream);

  // 1. casts
  cast_kernel<<<2048, 256, 0, stream>>>(x, Wq, Wk, Wv, Wo, Wf, Wd2,
                                        x_h, x8, wqvk, wo_h, wf_h, wd2h, N);
  // 2. enc tables
  enc_kernel<<<(4800 + 255) / 256, 256, 0, stream>>>(dist_emb, dir_emb, Wsp1, bsp1, Wsp2, bsp2, enc_tab);
  // 3. degree histograms
  hist_kernel<<<(E + 255) / 256, 256, 0, stream>>>(eidx, deg_i, indeg_i, E);
  // 4. scans -> CSR offsets
  scan_kernel<<<1, 1024, 0, stream>>>(indeg_i, deg_i, dptr, sptr, N);
  // 5. CSR scatter + edge bins
  scatter_kernel<<<(E + 255) / 256, 256, 0, stream>>>(eidx, coords, dptr, sptr,
                                                      fill_d, fill_s, erec, sdst, E);
  // 6. spatial density
  {
    dim3 g((N + 255) / 256, (N + 511) / 512);
    sp_kernel<<<g, 256, 0, stream>>>(coords, sp_i, N);
  }
  // 7. fvar (fp8 gathers, no atomics)
  fvar_kernel<<<(N + 3) / 4, 256, 0, stream>>>(x, x8, sptr, sdst, fvar, N);
  // 8. maxes via single-block tree reduction
  maxred_kernel<<<1, 1024, 0, stream>>>(sptr, sp_i, fvar, maxf, N);

  const int mtiles = Mp / 128;
  for (int s = 0; s < 3; ++s) {
    // density MLP
    h_kernel<<<(N * 128 + 255) / 256, 256, 0, stream>>>(sptr, sp_i, fvar, maxf,
                                                        Wd1 + s * 384, bd1 + s * 128, hbuf, N);
    gemm_bt_f16<<<dim3(mtiles, 2), 256, 0, stream>>>(hbuf, 128, wd2h + (size_t)s * 32768, 128,
                                                     bd2 + s * 256, dfr, 256, 128, Mp, 0,
                                                     nullptr, 0, 99);
    norm_kernel<<<(N + 3) / 4, 256, 0, stream>>>(dfr, drec8, N);
    // q,v (f16 -> nrec) and k (fp8 -> krec8) in one split-output GEMM
    gemm_bt_f16<<<dim3(mtiles, 6), 256, 0, stream>>>(x_h, 256, wqvk + (size_t)s * 196608, 256,
                                                     nullptr, nrec, 512, 256, Mp, 1,
                                                     (unsigned char*)krec8, 256, 4);
    // edge-wise attention + scatter softmax + aggregate
    edge_attn<<<(N + 3) / 4, 256, 0, stream>>>(nrec, krec8, drec8, erec, dptr,
                                               enc_tab + s * 1600, temp + s * 8, aggh, N, 7 * s);
    // output projection into concat buffer
    gemm_bt_f16<<<dim3(mtiles, 2), 256, 0, stream>>>(aggh, 256, wo_h + (size_t)s * 65536, 256,
                                                     bo + s * 256, outsh + s * 256, 768, 256, Mp, 1,
                                                     nullptr, 0, 99);
  }
  // fusion GEMM -> d_out (f32), guard rows < N
  gemm_bt_f16<<<dim3(mtiles, 2), 256, 0, stream>>>(outsh, 768, wf_h, 768,
                                                   bf, d_out, 256, 768, N, 0,
                                                   nullptr, 0, 99);
}

// Round 4
// 431.519 us; speedup vs baseline: 2.2984x; 1.3830x over previous
//
#include <hip/hip_runtime.h>

typedef _Float16 f16;
typedef _Float16 f16x4 __attribute__((ext_vector_type(4)));
typedef _Float16 f16x8 __attribute__((ext_vector_type(8)));
typedef float    f32x4 __attribute__((ext_vector_type(4)));
typedef float    fv2   __attribute__((ext_vector_type(2)));

__device__ __forceinline__ float4 ld4h(const f16* p) {
  f16x4 t = *(const f16x4*)p;
  return make_float4((float)t[0], (float)t[1], (float)t[2], (float)t[3]);
}

__device__ __forceinline__ float4 dec_fp8x4(unsigned u) {
  fv2 lo = __builtin_amdgcn_cvt_pk_f32_fp8(u, false);
  fv2 hi = __builtin_amdgcn_cvt_pk_f32_fp8(u, true);
  return make_float4(lo[0], lo[1], hi[0], hi[1]);
}

__device__ __forceinline__ unsigned enc_fp8x4(float a, float b, float c, float d) {
  unsigned v = 0;
  v = __builtin_amdgcn_cvt_pk_fp8_f32(a, b, v, false);
  v = __builtin_amdgcn_cvt_pk_fp8_f32(c, d, v, true);
  return v;
}

__device__ __forceinline__ void gld_lds16(const void* g, void* l) {
  __builtin_amdgcn_global_load_lds(
      (const __attribute__((address_space(1))) unsigned*)g,
      (__attribute__((address_space(3))) unsigned*)l, 16, 0, 0);
}

__device__ __forceinline__ int cell_of(const float* coords, int i) {
  int cx = (int)(coords[2 * i] * 0.02f);
  int cy = (int)(coords[2 * i + 1] * 0.02f);
  cx = cx < 0 ? 0 : (cx > 19 ? 19 : cx);
  cy = cy < 0 ? 0 : (cy > 19 ? 19 : cy);
  return cy * 20 + cx;
}

// ===================== pack: f32 -> f16/fp8 casts (x + all GEMM weights) =====================
// wqvk layout per scale: rows [0:256)=q, [256:512)=v, [512:768)=k  (k tiles feed fp8 output)
__global__ __launch_bounds__(256) void cast_kernel(
    const float* __restrict__ x, const float* __restrict__ Wq, const float* __restrict__ Wk,
    const float* __restrict__ Wv, const float* __restrict__ Wo, const float* __restrict__ Wf,
    const float* __restrict__ Wd2,
    f16* __restrict__ x_h, unsigned* __restrict__ x8, f16* __restrict__ wqvk,
    f16* __restrict__ wo_h, f16* __restrict__ wf_h, f16* __restrict__ wd2h, int N)
{
  const int n0 = N * 64;  // x elements in float4 units
  const int total = n0 + 147456 + 49152 + 49152 + 24576;
  for (int i = blockIdx.x * 256 + threadIdx.x; i < total; i += gridDim.x * 256) {
    int k = i;
    if (k < n0) {
      float4 v = ((const float4*)x)[k];
      f16x4 o; o[0] = (f16)v.x; o[1] = (f16)v.y; o[2] = (f16)v.z; o[3] = (f16)v.w;
      ((f16x4*)x_h)[k] = o;
      x8[k] = enc_fp8x4(v.x, v.y, v.z, v.w);
      continue;
    }
    const float4* sp; f16x4* dp;
    k -= n0;
    if (k < 147456) {  // q|v|k reorg
      int s = k / 49152, r = k % 49152, m = r / 16384, off = r % 16384;
      const float* w = (m == 0) ? Wq : (m == 1) ? Wk : Wv;
      int dblk = (m == 0) ? 0 : (m == 1) ? 32768 : 16384;
      sp = (const float4*)(w + s * 65536) + off;
      dp = (f16x4*)wqvk + s * 49152 + dblk + off;
    } else {
      k -= 147456;
      if (k < 49152) { sp = (const float4*)Wo + k; dp = (f16x4*)wo_h + k; }
      else {
        k -= 49152;
        if (k < 49152) { sp = (const float4*)Wf + k; dp = (f16x4*)wf_h + k; }
        else { k -= 49152; sp = (const float4*)Wd2 + k; dp = (f16x4*)wd2h + k; }
      }
    }
    float4 v = *sp;
    f16x4 o; o[0] = (f16)v.x; o[1] = (f16)v.y; o[2] = (f16)v.z; o[3] = (f16)v.w;
    *dp = o;
  }
}

// ===================== enc lookup table: [3][100][16] =====================
__global__ __launch_bounds__(256) void enc_kernel(
    const float* __restrict__ dist_emb, const float* __restrict__ dir_emb,
    const float* __restrict__ Wsp1, const float* __restrict__ bsp1,
    const float* __restrict__ Wsp2, const float* __restrict__ bsp2,
    float* __restrict__ enc_tab)
{
  int id = blockIdx.x * 256 + threadIdx.x;
  if (id >= 3 * 1600) return;
  int s = id / 1600, c = id % 1600, db = c >> 4, ab = c & 15;
  const float* de = dist_emb + (size_t)(s * 100 + db) * 16;
  const float* ae = dir_emb + (size_t)(s * 16 + ab) * 16;
  const float* w1 = Wsp1 + s * 1024;
  const float* b1 = bsp1 + s * 32;
  const float* w2 = Wsp2 + s * 32;
  float enc = bsp2[s];
  for (int j = 0; j < 32; ++j) {
    float a = b1[j];
    const float* wr = w1 + j * 32;
#pragma unroll
    for (int i = 0; i < 16; ++i) a += de[i] * wr[i];
#pragma unroll
    for (int i = 0; i < 16; ++i) a += ae[i] * wr[16 + i];
    enc += fmaxf(a, 0.0f) * w2[j];
  }
  enc_tab[id] = enc;
}

// ===================== degree histograms + cell histogram =====================
__global__ __launch_bounds__(256) void hist_kernel(const int* __restrict__ eidx,
                                                   const float* __restrict__ coords,
                                                   int* deg_i, int* indeg_i,
                                                   int* cellcnt, int E, int N)
{
  int e = blockIdx.x * 256 + threadIdx.x;
  if (e < E) {
    atomicAdd(&deg_i[eidx[e]], 1);
    atomicAdd(&indeg_i[eidx[E + e]], 1);
  }
  if (e < N) atomicAdd(&cellcnt[cell_of(coords, e)], 1);
}

// ===================== single-block exclusive scan: dptr, sptr, cptr =====================
__global__ __launch_bounds__(1024) void scan_kernel(const int* __restrict__ indeg,
                                                    const int* __restrict__ deg,
                                                    const int* __restrict__ cellcnt,
                                                    int* dptr, int* sptr, int* cptr, int N)
{
  __shared__ int lds[1024];
  const int tid = threadIdx.x;
  for (int pass = 0; pass < 3; ++pass) {
    const int* in = (pass == 0) ? indeg : (pass == 1) ? deg : cellcnt;
    int* out = (pass == 0) ? dptr : (pass == 1) ? sptr : cptr;
    int len = (pass == 2) ? 400 : N;
    int base = tid * 16;
    int loc[16];
    int sum = 0;
#pragma unroll
    for (int j = 0; j < 16; ++j) {
      int v = (base + j < len) ? in[base + j] : 0;
      loc[j] = sum; sum += v;
    }
    lds[tid] = sum;
    __syncthreads();
    for (int off = 1; off < 1024; off <<= 1) {
      int t = (tid >= off) ? lds[tid - off] : 0;
      __syncthreads();
      lds[tid] += t;
      __syncthreads();
    }
    int prev = tid ? lds[tid - 1] : 0;
#pragma unroll
    for (int j = 0; j < 16; ++j)
      if (base + j < len) out[base + j] = prev + loc[j];
    if (tid == 1023) out[len] = lds[1023];
    __syncthreads();
  }
}

// ===================== CSR scatter + per-edge geometry bins + cell scatter =====================
__global__ __launch_bounds__(256) void scatter_kernel(
    const int* __restrict__ eidx, const float* __restrict__ coords,
    const int* __restrict__ dptr, const int* __restrict__ sptr, const int* __restrict__ cptr,
    int* fill_d, int* fill_s, int* fill_c,
    int2* __restrict__ erec, int* __restrict__ sdst, float2* __restrict__ scoord, int E, int N)
{
  int e = blockIdx.x * 256 + threadIdx.x;
  if (e < E) {
    int s = eidx[e], d = eidx[E + e];
    float rx = coords[2 * s] - coords[2 * d];
    float ry = coords[2 * s + 1] - coords[2 * d + 1];
    float dist = sqrtf(rx * rx + ry * ry);
    float ang = atan2f(ry, rx);
    int ab = (int)((ang + 3.14159265358979323846f) / 6.28318530717958647692f * 15.0f);
    ab = ab < 0 ? 0 : (ab > 15 ? 15 : ab);
    int b0 = (int)((dist / 500.0f) * 99.0f);  b0 = b0 < 0 ? 0 : (b0 > 99 ? 99 : b0);
    int b1 = (int)((dist / 1000.0f) * 99.0f); b1 = b1 < 0 ? 0 : (b1 > 99 ? 99 : b1);
    int b2 = (int)((dist / 2000.0f) * 99.0f); b2 = b2 < 0 ? 0 : (b2 > 99 ? 99 : b2);
    unsigned pb = (unsigned)b0 | ((unsigned)b1 << 7) | ((unsigned)b2 << 14) | ((unsigned)ab << 21);
    int pd = dptr[d] + atomicAdd(&fill_d[d], 1);
    erec[pd] = make_int2(s, (int)pb);
    int ps = sptr[s] + atomicAdd(&fill_s[s], 1);
    sdst[ps] = d;
  }
  if (e < N) {
    int cid = cell_of(coords, e);
    int pc = cptr[cid] + atomicAdd(&fill_c[cid], 1);
    scoord[pc] = ((const float2*)coords)[e];
  }
}

// ===================== spatial density via 3x3 cell neighborhood, wave per node =====================
__global__ __launch_bounds__(256) void sp_count_kernel(
    const float* __restrict__ coords, const float2* __restrict__ scoord,
    const int* __restrict__ cptr, int* __restrict__ sp_i, int N)
{
  int wv = threadIdx.x >> 6, lane = threadIdx.x & 63;
  int node = blockIdx.x * 4 + wv;
  if (node >= N) return;
  float cx = coords[2 * node], cy = coords[2 * node + 1];
  int gx = (int)(cx * 0.02f); gx = gx < 0 ? 0 : (gx > 19 ? 19 : gx);
  int gy = (int)(cy * 0.02f); gy = gy < 0 ? 0 : (gy > 19 ? 19 : gy);
  int x0 = gx > 0 ? gx - 1 : 0, x1 = gx < 19 ? gx + 1 : 19;
  int y0 = gy > 0 ? gy - 1 : 0, y1 = gy < 19 ? gy + 1 : 19;
  int cnt = 0;
  for (int r = y0; r <= y1; ++r) {
    int j0 = cptr[r * 20 + x0], j1 = cptr[r * 20 + x1 + 1];
    for (int j = j0 + lane; j < j1; j += 64) {
      float2 c = scoord[j];
      float dx = cx - c.x, dy = cy - c.y;
      cnt += (dx * dx + dy * dy <= 2500.0f) ? 1 : 0;
    }
  }
  cnt += __shfl_xor(cnt, 1);  cnt += __shfl_xor(cnt, 2);  cnt += __shfl_xor(cnt, 4);
  cnt += __shfl_xor(cnt, 8);  cnt += __shfl_xor(cnt, 16); cnt += __shfl_xor(cnt, 32);
  if (lane == 0) sp_i[node] = cnt;   // includes self, like reference pre -1
}

// ===================== fvar (local feature variance), fp8 gathers, no atomics =====================
__global__ __launch_bounds__(256) void fvar_kernel(
    const float* __restrict__ x, const unsigned* __restrict__ x8,
    const int* __restrict__ sptr, const int* __restrict__ sdst,
    float* __restrict__ fvar, int N)
{
  int wv = threadIdx.x >> 6, lane = threadIdx.x & 63;
  int node = blockIdx.x * 4 + wv;
  if (node >= N) return;
  int e0 = sptr[node], e1 = sptr[node + 1];
  float sx = 0.f, sy = 0.f, sz = 0.f, sw = 0.f;
  for (int e = e0; e < e1; e += 2) {
    int d0 = __builtin_amdgcn_readfirstlane(sdst[e]);
    int d1 = __builtin_amdgcn_readfirstlane(sdst[(e + 1 < e1) ? e + 1 : e]);
    float w1 = (e + 1 < e1) ? 1.0f : 0.0f;
    float4 a = dec_fp8x4(x8[d0 * 64 + lane]);
    float4 b = dec_fp8x4(x8[d1 * 64 + lane]);
    sx += a.x + w1 * b.x; sy += a.y + w1 * b.y;
    sz += a.z + w1 * b.z; sw += a.w + w1 * b.w;
  }
  float cnt = fmaxf((float)(e1 - e0), 1.0f);
  float4 xm = ((const float4*)(x + (size_t)node * 256))[lane];
  float dx = xm.x - sx / cnt, dy = xm.y - sy / cnt, dz = xm.z - sz / cnt, dw = xm.w - sw / cnt;
  float ss = dx * dx + dy * dy + dz * dz + dw * dw;
  ss += __shfl_xor(ss, 1);  ss += __shfl_xor(ss, 2);  ss += __shfl_xor(ss, 4);
  ss += __shfl_xor(ss, 8);  ss += __shfl_xor(ss, 16); ss += __shfl_xor(ss, 32);
  if (lane == 0) fvar[node] = sqrtf(ss);
}

// ===================== global maxes: single block, LDS tree, zero atomics =====================
__global__ __launch_bounds__(1024) void maxred_kernel(
    const int* __restrict__ sptr, const int* __restrict__ sp_i,
    const float* __restrict__ fvar, float* __restrict__ maxf, int N)
{
  __shared__ float l0[1024], l1[1024], l2[1024];
  int tid = threadIdx.x;
  float m0 = 0.f, m1 = 0.f, m2 = 0.f;
  for (int i = tid; i < N; i += 1024) {
    m0 = fmaxf(m0, (float)(sptr[i + 1] - sptr[i]));
    m1 = fmaxf(m1, (float)(sp_i[i] - 1));
    m2 = fmaxf(m2, fvar[i]);
  }
  l0[tid] = m0; l1[tid] = m1; l2[tid] = m2;
  __syncthreads();
  for (int off = 512; off > 0; off >>= 1) {
    if (tid < off) {
      l0[tid] = fmaxf(l0[tid], l0[tid + off]);
      l1[tid] = fmaxf(l1[tid], l1[tid + off]);
      l2[tid] = fmaxf(l2[tid], l2[tid + off]);
    }
    __syncthreads();
  }
  if (tid == 0) { maxf[0] = l0[0]; maxf[1] = l1[0]; maxf[2] = l2[0]; }
}

// ===================== per-scale hidden h = relu(dens @ Wd1^T + bd1), batched over scales =====================
__global__ __launch_bounds__(256) void h_kernel(
    const int* __restrict__ sptr, const int* __restrict__ sp_i, const float* __restrict__ fvar,
    const float* __restrict__ maxf, const float* __restrict__ Wd1,
    const float* __restrict__ bd1, f16* __restrict__ hbuf, int N, int Mp)
{
  int id = blockIdx.x * 256 + threadIdx.x;
  if (id >= N * 128) return;
  int s = blockIdx.y;
  int node = id >> 7, j = id & 127;
  float dm = maxf[0] + 1e-8f;
  float sm = maxf[1] + 1e-8f;
  float fm = maxf[2] + 1e-8f;
  float d0 = (float)(sptr[node + 1] - sptr[node]) / dm;
  float d1 = (float)(sp_i[node] - 1) / sm;
  float d2 = fvar[node] / fm;
  const float* wr = Wd1 + s * 384 + j * 3;
  float h = fmaxf(wr[0] * d0 + wr[1] * d1 + wr[2] * d2 + bd1[s * 128 + j], 0.0f);
  hbuf[(size_t)s * Mp * 128 + (size_t)node * 128 + j] = (f16)h;
}

// ===================== fp16 MFMA GEMM, scale-batched (blockIdx.z), split fp8 output =====================
// C[M,N] = A[M,K] @ B[N,K]^T (+bias); y-tiles >= ysplit write fp8 to Cv2 (rebased cols).
__global__ __launch_bounds__(256) void gemm_bt_f16(
    const f16* __restrict__ A, int lda, long sA,
    const f16* __restrict__ B, int ldb, long sB,
    const float* __restrict__ bias, int sBias,
    void* __restrict__ Cv, int ldc, long sC, int K, int Mstore, int outMode,
    unsigned char* __restrict__ Cv2, int ldc2, long sC2, int ysplit)
{
  __shared__ f16 As[128 * 64];
  __shared__ f16 Bs[128 * 64];
  const int s = blockIdx.z;
  const int tid = threadIdx.x;
  const int lane = tid & 63;
  const int w = tid >> 6;
  const int wr = (w >> 1) * 64, wc = (w & 1) * 64;
  const int srow = tid >> 3;
  const int scol = (tid & 7) * 8;
  const f16* Ab = A + (size_t)s * sA + (size_t)(blockIdx.x * 128 + srow) * lda + scol;
  const f16* Bb = B + (size_t)s * sB + (size_t)(blockIdx.y * 128 + srow) * ldb + scol;
  char* Asl = (char*)As + tid * 16;
  char* Bsl = (char*)Bs + tid * 16;

  f32x4 acc[4][4] = {};

  for (int kt = 0; kt < K; kt += 64) {
    __syncthreads();
#pragma unroll
    for (int i = 0; i < 4; ++i) {
      gld_lds16(Ab + (size_t)i * 32 * lda + kt, Asl + i * 4096);
      gld_lds16(Bb + (size_t)i * 32 * ldb + kt, Bsl + i * 4096);
    }
    __syncthreads();
#pragma unroll
    for (int kq = 0; kq < 2; ++kq) {
      const int krd = kq * 32 + (lane >> 4) * 8;
      f16x8 af[4], bfr[4];
#pragma unroll
      for (int t = 0; t < 4; ++t) {
        af[t]  = *(const f16x8*)&As[(wr + t * 16 + (lane & 15)) * 64 + krd];
        bfr[t] = *(const f16x8*)&Bs[(wc + t * 16 + (lane & 15)) * 64 + krd];
      }
#pragma unroll
      for (int mi = 0; mi < 4; ++mi)
#pragma unroll
        for (int ni = 0; ni < 4; ++ni)
          acc[mi][ni] = __builtin_amdgcn_mfma_f32_16x16x32_f16(af[mi], bfr[ni], acc[mi][ni], 0, 0, 0);
    }
  }

  const int r0 = (lane >> 4) << 2;
  const int c0 = lane & 15;
  const bool f8p = ((int)blockIdx.y >= ysplit);
  const int cbase = f8p ? ((int)blockIdx.y - ysplit) * 128 : (int)blockIdx.y * 128;
#pragma unroll
  for (int mi = 0; mi < 4; ++mi) {
#pragma unroll
    for (int ni = 0; ni < 4; ++ni) {
      int col = cbase + wc + ni * 16 + c0;
      float bv = (!f8p && bias) ? bias[s * sBias + col] : 0.0f;
#pragma unroll
      for (int r = 0; r < 4; ++r) {
        int row = blockIdx.x * 128 + wr + mi * 16 + r0 + r;
        if (row < Mstore) {
          float v = acc[mi][ni][r] + bv;
          if (f8p) {
            unsigned pk = __builtin_amdgcn_cvt_pk_fp8_f32(v, v, 0u, false);
            Cv2[(size_t)s * sC2 + (size_t)row * ldc2 + col] = (unsigned char)(pk & 0xffu);
          } else if (outMode == 1) {
            ((f16*)Cv)[(size_t)s * sC + (size_t)row * ldc + col] = (f16)v;
          } else {
            ((float*)Cv)[(size_t)s * sC + (size_t)row * ldc + col] = v;
          }
        }
      }
    }
  }
}

// ===================== normalize df rows -> dfn (fp8), batched over scales =====================
__global__ __launch_bounds__(256) void norm_kernel(const f16* __restrict__ dfh,
                                                   unsigned* __restrict__ drec8, int N, int Mp)
{
  int wv = threadIdx.x >> 6, lane = threadIdx.x & 63;
  int node = blockIdx.x * 4 + wv;
  if (node >= N) return;
  int s = blockIdx.y;
  float4 d = ld4h(dfh + (size_t)s * Mp * 256 + (size_t)node * 256 + lane * 4);
  float ss = d.x * d.x + d.y * d.y + d.z * d.z + d.w * d.w;
  ss += __shfl_xor(ss, 1);  ss += __shfl_xor(ss, 2);  ss += __shfl_xor(ss, 4);
  ss += __shfl_xor(ss, 8);  ss += __shfl_xor(ss, 16); ss += __shfl_xor(ss, 32);
  float rn = 1.0f / fmaxf(sqrtf(ss), 1e-8f);
  drec8[(size_t)s * Mp * 64 + node * 64 + lane] = enc_fp8x4(d.x * rn, d.y * rn, d.z * rn, d.w * rn);
}

// ===================== edge attention: one wave per destination node, batched over scales =====================
// nrec row (per node, f16, 512): [0:256)=q [256:512)=v ; krec8/drec8: fp8 256B rows
__global__ __launch_bounds__(256) void edge_attn(
    const f16* __restrict__ nrec0, const unsigned* __restrict__ krec0,
    const unsigned* __restrict__ drec0, const int2* __restrict__ erec,
    const int* __restrict__ dptr, const float* __restrict__ enc_tab,
    const float* __restrict__ temp, f16* __restrict__ aggh0, int N, int Mp)
{
  int wv = threadIdx.x >> 6, lane = threadIdx.x & 63;
  int node = blockIdx.x * 4 + wv;
  if (node >= N) return;
  const int s = blockIdx.y;
  const int sshift = 7 * s;
  const f16* nrec = nrec0 + (size_t)s * Mp * 512;
  const unsigned* krec8 = krec0 + (size_t)s * Mp * 64;
  const unsigned* drec8 = drec0 + (size_t)s * Mp * 64;
  const float* enc_s = enc_tab + s * 1600;
  f16* aggh = aggh0 + (size_t)s * Mp * 256;

  float4 q = ld4h(nrec + (size_t)node * 512 + lane * 4);
  float4 dfi = dec_fp8x4(drec8[node * 64 + lane]);
  float th = temp[s * 8 + (lane >> 3)];
  float m = -INFINITY, z = 0.0f;
  float ax = 0.f, ay = 0.f, az = 0.f, aw = 0.f;
  int e0 = dptr[node], e1 = dptr[node + 1];
  if (e0 < e1) {
    int2 r0 = erec[e0];
    int2 r1 = erec[(e0 + 1 < e1) ? e0 + 1 : e0];
    for (int e = e0; e < e1; e += 2) {
      int s0 = __builtin_amdgcn_readfirstlane(r0.x);
      unsigned pb0 = (unsigned)__builtin_amdgcn_readfirstlane(r0.y);
      int s1 = __builtin_amdgcn_readfirstlane(r1.x);
      unsigned pb1 = (unsigned)__builtin_amdgcn_readfirstlane(r1.y);
      int en0 = (e + 2 < e1) ? e + 2 : e1 - 1;
      int en1 = (e + 3 < e1) ? e + 3 : e1 - 1;
      r0 = erec[en0]; r1 = erec[en1];
      unsigned ku0 = krec8[s0 * 64 + lane];
      unsigned du0 = drec8[s0 * 64 + lane];
      float4 v0 = ld4h(nrec + (size_t)s0 * 512 + 256 + lane * 4);
      unsigned ku1 = krec8[s1 * 64 + lane];
      unsigned du1 = drec8[s1 * 64 + lane];
      float4 v1 = ld4h(nrec + (size_t)s1 * 512 + 256 + lane * 4);
      float4 k0 = dec_fp8x4(ku0), d0 = dec_fp8x4(du0);
      float4 k1 = dec_fp8x4(ku1), d1 = dec_fp8x4(du1);
      float qk0 = q.x * k0.x + q.y * k0.y + q.z * k0.z + q.w * k0.w;
      float ds0 = dfi.x * d0.x + dfi.y * d0.y + dfi.z * d0.z + dfi.w * d0.w;
      float qk1 = q.x * k1.x + q.y * k1.y + q.z * k1.z + q.w * k1.w;
      float ds1 = dfi.x * d1.x + dfi.y * d1.y + dfi.z * d1.z + dfi.w * d1.w;
      qk0 += __shfl_xor(qk0, 1); qk1 += __shfl_xor(qk1, 1);
      ds0 += __shfl_xor(ds0, 1); ds1 += __shfl_xor(ds1, 1);
      qk0 += __shfl_xor(qk0, 2); qk1 += __shfl_xor(qk1, 2);
      ds0 += __shfl_xor(ds0, 2); ds1 += __shfl_xor(ds1, 2);
      qk0 += __shfl_xor(qk0, 4); qk1 += __shfl_xor(qk1, 4);
      ds0 += __shfl_xor(ds0, 4); ds1 += __shfl_xor(ds1, 4);
      ds0 += __shfl_xor(ds0, 8); ds1 += __shfl_xor(ds1, 8);
      ds0 += __shfl_xor(ds0, 16); ds1 += __shfl_xor(ds1, 16);
      ds0 += __shfl_xor(ds0, 32); ds1 += __shfl_xor(ds1, 32);
      float enc0 = enc_s[((pb0 >> sshift) & 127u) * 16 + (pb0 >> 21)];
      float enc1 = enc_s[((pb1 >> sshift) & 127u) * 16 + (pb1 >> 21)];
      float sc0 = (qk0 * 0.17677669529663687f / th + enc0) * (1.0f + 0.5f * ds0);
      float sc1 = (qk1 * 0.17677669529663687f / th + enc1) * (1.0f + 0.5f * ds1);
      if (e + 1 >= e1) sc1 = -1e30f;  // odd tail: edge1 is a duplicate, zero its weight
      float mn = fmaxf(m, fmaxf(sc0, sc1));
      float rs = __expf(m - mn);
      float p0 = __expf(sc0 - mn);
      float p1 = __expf(sc1 - mn);
      z = z * rs + p0 + p1;
      ax = ax * rs + p0 * v0.x + p1 * v1.x;
      ay = ay * rs + p0 * v0.y + p1 * v1.y;
      az = az * rs + p0 * v0.z + p1 * v1.z;
      aw = aw * rs + p0 * v0.w + p1 * v1.w;
      m = mn;
    }
  }
  float rz = 1.0f / (z + 1e-16f);
  f16x4 o; o[0] = (f16)(ax * rz); o[1] = (f16)(ay * rz); o[2] = (f16)(az * rz); o[3] = (f16)(aw * rz);
  ((f16x4*)(aggh + (size_t)node * 256))[lane] = o;
}

// ===================== host launcher =====================
extern "C" void kernel_launch(void* const* d_in, const int* in_sizes, int n_in,
                              void* d_out, int out_size, void* d_ws, size_t ws_size,
                              hipStream_t stream)
{
  const float* x      = (const float*)d_in[0];
  const float* coords = (const float*)d_in[1];
  const int*   eidx   = (const int*)  d_in[2];
  const float* Wq   = (const float*)d_in[3];
  const float* Wk   = (const float*)d_in[4];
  const float* Wv   = (const float*)d_in[5];
  const float* Wo   = (const float*)d_in[6];
  const float* bo   = (const float*)d_in[7];
  const float* temp = (const float*)d_in[8];
  const float* dist_emb = (const float*)d_in[9];
  const float* dir_emb  = (const float*)d_in[10];
  const float* Wsp1 = (const float*)d_in[11];
  const float* bsp1 = (const float*)d_in[12];
  const float* Wsp2 = (const float*)d_in[13];
  const float* bsp2 = (const float*)d_in[14];
  const float* Wd1  = (const float*)d_in[15];
  const float* bd1  = (const float*)d_in[16];
  const float* Wd2  = (const float*)d_in[17];
  const float* bd2  = (const float*)d_in[18];
  const float* Wf   = (const float*)d_in[19];
  const float* bf   = (const float*)d_in[20];
  (void)n_in; (void)out_size; (void)ws_size;

  const int N  = in_sizes[0] / 256;
  const int E  = in_sizes[2] / 2;
  const int Mp = ((N + 127) / 128) * 128;

  char* p = (char*)d_ws;
  auto alloc = [&](size_t b) -> void* {
    void* r = (void*)p;
    p += (b + 255) & ~(size_t)255;
    return r;
  };

  f16*      x_h   = (f16*)     alloc((size_t)Mp * 256 * 2);
  unsigned* x8    = (unsigned*)alloc((size_t)Mp * 256);
  f16*      nrec3 = (f16*)     alloc((size_t)3 * Mp * 512 * 2);  // q|v per node per scale
  unsigned* krec3 = (unsigned*)alloc((size_t)3 * Mp * 256);
  unsigned* drec3 = (unsigned*)alloc((size_t)3 * Mp * 256);
  f16*      hbuf3 = (f16*)     alloc((size_t)3 * Mp * 128 * 2);
  f16*      dfh3  = (f16*)     alloc((size_t)3 * Mp * 256 * 2);
  f16*      aggh3 = (f16*)     alloc((size_t)3 * Mp * 256 * 2);
  f16*      outsh = (f16*)     alloc((size_t)Mp * 768 * 2);
  f16*      wqvk  = (f16*)     alloc((size_t)3 * 768 * 256 * 2);
  f16*      wo_h  = (f16*)     alloc((size_t)3 * 256 * 256 * 2);
  f16*      wf_h  = (f16*)     alloc((size_t)256 * 768 * 2);
  f16*      wd2h  = (f16*)     alloc((size_t)3 * 256 * 128 * 2);
  float*    enc_tab = (float*) alloc((size_t)3 * 1600 * 4);
  int*    dptr = (int*)   alloc((size_t)(N + 1) * 4);
  int*    sptr = (int*)   alloc((size_t)(N + 1) * 4);
  int*    cptr = (int*)   alloc((size_t)401 * 4);
  int2*   erec = (int2*)  alloc((size_t)E * 8);
  int*    sdst = (int*)   alloc((size_t)E * 4);
  float2* scoord = (float2*)alloc((size_t)N * 8);
  float*  fvar = (float*) alloc((size_t)N * 4);
  int*    sp_i = (int*)   alloc((size_t)N * 4);
  float*  maxf = (float*) alloc(4 * 4);
  // ---- zeroed-every-call block ----
  char* z0 = p;
  int* deg_i   = (int*)alloc((size_t)N * 4);
  int* indeg_i = (int*)alloc((size_t)N * 4);
  int* fill_d  = (int*)alloc((size_t)N * 4);
  int* fill_s  = (int*)alloc((size_t)N * 4);
  int* cellcnt = (int*)alloc(400 * 4);
  int* fill_c  = (int*)alloc(400 * 4);
  size_t zbytes = (size_t)(p - z0);
  hipMemsetAsync(z0, 0, zbytes, stream);

  // 1. casts
  cast_kernel<<<2048, 256, 0, stream>>>(x, Wq, Wk, Wv, Wo, Wf, Wd2,
                                        x_h, x8, wqvk, wo_h, wf_h, wd2h, N);
  // 2. enc tables
  enc_kernel<<<(4800 + 255) / 256, 256, 0, stream>>>(dist_emb, dir_emb, Wsp1, bsp1, Wsp2, bsp2, enc_tab);
  // 3. degree + cell histograms
  hist_kernel<<<(E + 255) / 256, 256, 0, stream>>>(eidx, coords, deg_i, indeg_i, cellcnt, E, N);
  // 4. scans -> CSR offsets (dst, src, cells)
  scan_kernel<<<1, 1024, 0, stream>>>(indeg_i, deg_i, cellcnt, dptr, sptr, cptr, N);
  // 5. CSR scatter + edge bins + cell scatter
  scatter_kernel<<<(E + 255) / 256, 256, 0, stream>>>(eidx, coords, dptr, sptr, cptr,
                                                      fill_d, fill_s, fill_c, erec, sdst, scoord, E, N);
  // 6. spatial density via cells
  sp_count_kernel<<<(N + 3) / 4, 256, 0, stream>>>(coords, scoord, cptr, sp_i, N);
  // 7. fvar (fp8 gathers, no atomics)
  fvar_kernel<<<(N + 3) / 4, 256, 0, stream>>>(x, x8, sptr, sdst, fvar, N);
  // 8. maxes via single-block tree reduction
  maxred_kernel<<<1, 1024, 0, stream>>>(sptr, sp_i, fvar, maxf, N);

  const int mtiles = Mp / 128;
  // 9. density hidden layer, all scales
  h_kernel<<<dim3((N * 128 + 255) / 256, 3), 256, 0, stream>>>(sptr, sp_i, fvar, maxf,
                                                               Wd1, bd1, hbuf3, N, Mp);
  // 10. df = h @ Wd2^T + bd2 (f16), all scales
  gemm_bt_f16<<<dim3(mtiles, 2, 3), 256, 0, stream>>>(hbuf3, 128, (long)Mp * 128,
                                                      wd2h, 128, 32768, bd2, 256,
                                                      dfh3, 256, (long)Mp * 256, 128, Mp, 1,
                                                      nullptr, 0, 0, 99);
  // 11. normalize -> fp8 dfn, all scales
  norm_kernel<<<dim3((N + 3) / 4, 3), 256, 0, stream>>>(dfh3, drec3, N, Mp);
  // 12. q,v (f16) and k (fp8) in one split-output GEMM, all scales
  gemm_bt_f16<<<dim3(mtiles, 6, 3), 256, 0, stream>>>(x_h, 256, 0,
                                                      wqvk, 256, 196608, nullptr, 0,
                                                      nrec3, 512, (long)Mp * 512, 256, Mp, 1,
                                                      (unsigned char*)krec3, 256, (long)Mp * 256, 4);
  // 13. edge attention + scatter softmax + aggregate, all scales
  edge_attn<<<dim3((N + 3) / 4, 3), 256, 0, stream>>>(nrec3, krec3, drec3, erec, dptr,
                                                      enc_tab, temp, aggh3, N, Mp);
  // 14. output projection into concat buffer, all scales
  gemm_bt_f16<<<dim3(mtiles, 2, 3), 256, 0, stream>>>(aggh3, 256, (long)Mp * 256,
                                                      wo_h, 256, 65536, bo, 256,
                                                      outsh, 768, 256, 256, Mp, 1,
                                                      nullptr, 0, 0, 99);
  // 15. fusion GEMM -> d_out (f32), guard rows < N
  gemm_bt_f16<<<dim3(mtiles, 2, 1), 256, 0, stream>>>(outsh, 768, 0,
                                                      wf_h, 768, 0, bf, 0,
                                                      d_out, 256, 0, 768, N, 0,
                                                      nullptr, 0, 0, 99);
}

// Round 5
// 419.028 us; speedup vs baseline: 2.3669x; 1.0298x over previous
//
#include <hip/hip_runtime.h>

typedef _Float16 f16;
typedef _Float16 f16x4 __attribute__((ext_vector_type(4)));
typedef _Float16 f16x8 __attribute__((ext_vector_type(8)));
typedef float    f32x4 __attribute__((ext_vector_type(4)));
typedef float    fv2   __attribute__((ext_vector_type(2)));

__device__ __forceinline__ float4 ld4h(const f16* p) {
  f16x4 t = *(const f16x4*)p;
  return make_float4((float)t[0], (float)t[1], (float)t[2], (float)t[3]);
}

__device__ __forceinline__ float4 dec_fp8x4(unsigned u) {
  fv2 lo = __builtin_amdgcn_cvt_pk_f32_fp8(u, false);
  fv2 hi = __builtin_amdgcn_cvt_pk_f32_fp8(u, true);
  return make_float4(lo[0], lo[1], hi[0], hi[1]);
}

__device__ __forceinline__ unsigned enc_fp8x4(float a, float b, float c, float d) {
  unsigned v = 0;
  v = __builtin_amdgcn_cvt_pk_fp8_f32(a, b, v, false);
  v = __builtin_amdgcn_cvt_pk_fp8_f32(c, d, v, true);
  return v;
}

__device__ __forceinline__ void gld_lds16(const void* g, void* l) {
  __builtin_amdgcn_global_load_lds(
      (const __attribute__((address_space(1))) unsigned*)g,
      (__attribute__((address_space(3))) unsigned*)l, 16, 0, 0);
}

__device__ __forceinline__ int cell_of(const float* coords, int i) {
  int cx = (int)(coords[2 * i] * 0.02f);
  int cy = (int)(coords[2 * i + 1] * 0.02f);
  cx = cx < 0 ? 0 : (cx > 19 ? 19 : cx);
  cy = cy < 0 ? 0 : (cy > 19 ? 19 : cy);
  return cy * 20 + cx;
}

// ===================== pack: f32 -> f16/fp8 casts (x + all GEMM weights) =====================
// wqvk layout per scale: rows [0:256)=q, [256:512)=v, [512:768)=k  (k tiles feed fp8 output)
__global__ __launch_bounds__(256) void cast_kernel(
    const float* __restrict__ x, const float* __restrict__ Wq, const float* __restrict__ Wk,
    const float* __restrict__ Wv, const float* __restrict__ Wo, const float* __restrict__ Wf,
    const float* __restrict__ Wd2,
    f16* __restrict__ x_h, unsigned* __restrict__ x8, f16* __restrict__ wqvk,
    f16* __restrict__ wo_h, f16* __restrict__ wf_h, f16* __restrict__ wd2h, int N)
{
  const int n0 = N * 64;  // x elements in float4 units
  const int total = n0 + 147456 + 49152 + 49152 + 24576;
  for (int i = blockIdx.x * 256 + threadIdx.x; i < total; i += gridDim.x * 256) {
    int k = i;
    if (k < n0) {
      float4 v = ((const float4*)x)[k];
      f16x4 o; o[0] = (f16)v.x; o[1] = (f16)v.y; o[2] = (f16)v.z; o[3] = (f16)v.w;
      ((f16x4*)x_h)[k] = o;
      x8[k] = enc_fp8x4(v.x, v.y, v.z, v.w);
      continue;
    }
    const float4* sp; f16x4* dp;
    k -= n0;
    if (k < 147456) {  // q|v|k reorg
      int s = k / 49152, r = k % 49152, m = r / 16384, off = r % 16384;
      const float* w = (m == 0) ? Wq : (m == 1) ? Wk : Wv;
      int dblk = (m == 0) ? 0 : (m == 1) ? 32768 : 16384;
      sp = (const float4*)(w + s * 65536) + off;
      dp = (f16x4*)wqvk + s * 49152 + dblk + off;
    } else {
      k -= 147456;
      if (k < 49152) { sp = (const float4*)Wo + k; dp = (f16x4*)wo_h + k; }
      else {
        k -= 49152;
        if (k < 49152) { sp = (const float4*)Wf + k; dp = (f16x4*)wf_h + k; }
        else { k -= 49152; sp = (const float4*)Wd2 + k; dp = (f16x4*)wd2h + k; }
      }
    }
    float4 v = *sp;
    f16x4 o; o[0] = (f16)v.x; o[1] = (f16)v.y; o[2] = (f16)v.z; o[3] = (f16)v.w;
    *dp = o;
  }
}

// ===================== enc lookup table: [3][100][16] =====================
__global__ __launch_bounds__(256) void enc_kernel(
    const float* __restrict__ dist_emb, const float* __restrict__ dir_emb,
    const float* __restrict__ Wsp1, const float* __restrict__ bsp1,
    const float* __restrict__ Wsp2, const float* __restrict__ bsp2,
    float* __restrict__ enc_tab)
{
  int id = blockIdx.x * 256 + threadIdx.x;
  if (id >= 3 * 1600) return;
  int s = id / 1600, c = id % 1600, db = c >> 4, ab = c & 15;
  const float* de = dist_emb + (size_t)(s * 100 + db) * 16;
  const float* ae = dir_emb + (size_t)(s * 16 + ab) * 16;
  const float* w1 = Wsp1 + s * 1024;
  const float* b1 = bsp1 + s * 32;
  const float* w2 = Wsp2 + s * 32;
  float enc = bsp2[s];
  for (int j = 0; j < 32; ++j) {
    float a = b1[j];
    const float* wr = w1 + j * 32;
#pragma unroll
    for (int i = 0; i < 16; ++i) a += de[i] * wr[i];
#pragma unroll
    for (int i = 0; i < 16; ++i) a += ae[i] * wr[16 + i];
    enc += fmaxf(a, 0.0f) * w2[j];
  }
  enc_tab[id] = enc;
}

// ===================== degree histograms + cell histogram =====================
__global__ __launch_bounds__(256) void hist_kernel(const int* __restrict__ eidx,
                                                   const float* __restrict__ coords,
                                                   int* deg_i, int* indeg_i,
                                                   int* cellcnt, int E, int N)
{
  int e = blockIdx.x * 256 + threadIdx.x;
  if (e < E) {
    atomicAdd(&deg_i[eidx[e]], 1);
    atomicAdd(&indeg_i[eidx[E + e]], 1);
  }
  if (e < N) atomicAdd(&cellcnt[cell_of(coords, e)], 1);
}

// ===================== exclusive scans: one block per pass (dptr, sptr, cptr) =====================
__global__ __launch_bounds__(1024) void scan_kernel(const int* __restrict__ indeg,
                                                    const int* __restrict__ deg,
                                                    const int* __restrict__ cellcnt,
                                                    int* dptr, int* sptr, int* cptr, int N)
{
  __shared__ int lds[1024];
  const int tid = threadIdx.x;
  const int pass = blockIdx.x;
  const int* in = (pass == 0) ? indeg : (pass == 1) ? deg : cellcnt;
  int* out = (pass == 0) ? dptr : (pass == 1) ? sptr : cptr;
  int len = (pass == 2) ? 400 : N;
  int base = tid * 16;
  int loc[16];
  int sum = 0;
#pragma unroll
  for (int j = 0; j < 16; ++j) {
    int v = (base + j < len) ? in[base + j] : 0;
    loc[j] = sum; sum += v;
  }
  lds[tid] = sum;
  __syncthreads();
  for (int off = 1; off < 1024; off <<= 1) {
    int t = (tid >= off) ? lds[tid - off] : 0;
    __syncthreads();
    lds[tid] += t;
    __syncthreads();
  }
  int prev = tid ? lds[tid - 1] : 0;
#pragma unroll
  for (int j = 0; j < 16; ++j)
    if (base + j < len) out[base + j] = prev + loc[j];
  if (tid == 1023) out[len] = lds[1023];
}

// ===================== CSR scatter + per-edge geometry bins + cell scatter =====================
__global__ __launch_bounds__(256) void scatter_kernel(
    const int* __restrict__ eidx, const float* __restrict__ coords,
    const int* __restrict__ dptr, const int* __restrict__ sptr, const int* __restrict__ cptr,
    int* fill_d, int* fill_s, int* fill_c,
    int2* __restrict__ erec, int* __restrict__ sdst, float2* __restrict__ scoord, int E, int N)
{
  int e = blockIdx.x * 256 + threadIdx.x;
  if (e < E) {
    int s = eidx[e], d = eidx[E + e];
    float rx = coords[2 * s] - coords[2 * d];
    float ry = coords[2 * s + 1] - coords[2 * d + 1];
    float dist = sqrtf(rx * rx + ry * ry);
    float ang = atan2f(ry, rx);
    int ab = (int)((ang + 3.14159265358979323846f) / 6.28318530717958647692f * 15.0f);
    ab = ab < 0 ? 0 : (ab > 15 ? 15 : ab);
    int b0 = (int)((dist / 500.0f) * 99.0f);  b0 = b0 < 0 ? 0 : (b0 > 99 ? 99 : b0);
    int b1 = (int)((dist / 1000.0f) * 99.0f); b1 = b1 < 0 ? 0 : (b1 > 99 ? 99 : b1);
    int b2 = (int)((dist / 2000.0f) * 99.0f); b2 = b2 < 0 ? 0 : (b2 > 99 ? 99 : b2);
    unsigned pb = (unsigned)b0 | ((unsigned)b1 << 7) | ((unsigned)b2 << 14) | ((unsigned)ab << 21);
    int pd = dptr[d] + atomicAdd(&fill_d[d], 1);
    erec[pd] = make_int2(s, (int)pb);
    int ps = sptr[s] + atomicAdd(&fill_s[s], 1);
    sdst[ps] = d;
  }
  if (e < N) {
    int cid = cell_of(coords, e);
    int pc = cptr[cid] + atomicAdd(&fill_c[cid], 1);
    scoord[pc] = ((const float2*)coords)[e];
  }
}

// ===================== node stats: spatial density (cells) + fvar (slot-layout), wave/node =====================
__global__ __launch_bounds__(256) void node_stats_kernel(
    const float* __restrict__ coords, const float2* __restrict__ scoord,
    const int* __restrict__ cptr,
    const float* __restrict__ x, const unsigned* __restrict__ x8,
    const int* __restrict__ sptr, const int* __restrict__ sdst,
    int* __restrict__ sp_i, float* __restrict__ fvar, int N)
{
  int wv = threadIdx.x >> 6, lane = threadIdx.x & 63;
  int node = blockIdx.x * 4 + wv;
  if (node >= N) return;

  // --- spatial density via 3x3 cells ---
  float cx = coords[2 * node], cy = coords[2 * node + 1];
  {
    int gx = (int)(cx * 0.02f); gx = gx < 0 ? 0 : (gx > 19 ? 19 : gx);
    int gy = (int)(cy * 0.02f); gy = gy < 0 ? 0 : (gy > 19 ? 19 : gy);
    int x0 = gx > 0 ? gx - 1 : 0, x1 = gx < 19 ? gx + 1 : 19;
    int y0 = gy > 0 ? gy - 1 : 0, y1 = gy < 19 ? gy + 1 : 19;
    int cnt = 0;
    for (int r = y0; r <= y1; ++r) {
      int j0 = cptr[r * 20 + x0], j1 = cptr[r * 20 + x1 + 1];
      for (int j = j0 + lane; j < j1; j += 64) {
        float2 c = scoord[j];
        float dx = cx - c.x, dy = cy - c.y;
        cnt += (dx * dx + dy * dy <= 2500.0f) ? 1 : 0;
      }
    }
    cnt += __shfl_xor(cnt, 1);  cnt += __shfl_xor(cnt, 2);  cnt += __shfl_xor(cnt, 4);
    cnt += __shfl_xor(cnt, 8);  cnt += __shfl_xor(cnt, 16); cnt += __shfl_xor(cnt, 32);
    if (lane == 0) sp_i[node] = cnt;   // includes self (reference counts self, then -1)
  }

  // --- fvar: slot(8) x dimgroup(8) layout, 8 neighbors in flight ---
  const int slot = lane >> 3, w = lane & 7;
  float sum[32];
#pragma unroll
  for (int i = 0; i < 32; ++i) sum[i] = 0.f;
  int e0 = sptr[node], e1 = sptr[node + 1];
  int nit = (e1 - e0 + 7) >> 3;
  for (int it = 0; it < nit; ++it) {
    int e = e0 + it * 8 + slot;
    bool valid = e < e1;
    int dd = sdst[valid ? e : e1 - 1];
    const unsigned* xp = x8 + dd * 64 + w * 8;
    uint4 a = *(const uint4*)xp;
    uint4 b = *(const uint4*)(xp + 4);
    float vm = valid ? 1.f : 0.f;
    unsigned wd[8] = {a.x, a.y, a.z, a.w, b.x, b.y, b.z, b.w};
#pragma unroll
    for (int k = 0; k < 8; ++k) {
      float4 f = dec_fp8x4(wd[k]);
      sum[k*4+0] = fmaf(vm, f.x, sum[k*4+0]);
      sum[k*4+1] = fmaf(vm, f.y, sum[k*4+1]);
      sum[k*4+2] = fmaf(vm, f.z, sum[k*4+2]);
      sum[k*4+3] = fmaf(vm, f.w, sum[k*4+3]);
    }
  }
#pragma unroll
  for (int i = 0; i < 32; ++i) {
    sum[i] += __shfl_xor(sum[i], 8);
    sum[i] += __shfl_xor(sum[i], 16);
    sum[i] += __shfl_xor(sum[i], 32);
  }
  float rcnt = 1.0f / fmaxf((float)(e1 - e0), 1.0f);
  const float4* xp4 = (const float4*)(x + (size_t)node * 256 + w * 32);
  float ss = 0.f;
#pragma unroll
  for (int k = 0; k < 8; ++k) {
    float4 xm = xp4[k];
    float d0 = xm.x - sum[k*4+0] * rcnt;
    float d1 = xm.y - sum[k*4+1] * rcnt;
    float d2 = xm.z - sum[k*4+2] * rcnt;
    float d3 = xm.w - sum[k*4+3] * rcnt;
    ss += d0*d0 + d1*d1 + d2*d2 + d3*d3;
  }
  ss += __shfl_xor(ss, 1);  ss += __shfl_xor(ss, 2);  ss += __shfl_xor(ss, 4);
  ss += __shfl_xor(ss, 8);  ss += __shfl_xor(ss, 16); ss += __shfl_xor(ss, 32);
  if (lane == 0) fvar[node] = sqrtf(ss * 0.125f);   // 8 slot-copies of each dim group
}

// ===================== global maxes: single block, LDS tree, zero atomics =====================
__global__ __launch_bounds__(1024) void maxred_kernel(
    const int* __restrict__ sptr, const int* __restrict__ sp_i,
    const float* __restrict__ fvar, float* __restrict__ maxf, int N)
{
  __shared__ float l0[1024], l1[1024], l2[1024];
  int tid = threadIdx.x;
  float m0 = 0.f, m1 = 0.f, m2 = 0.f;
  for (int i = tid; i < N; i += 1024) {
    m0 = fmaxf(m0, (float)(sptr[i + 1] - sptr[i]));
    m1 = fmaxf(m1, (float)(sp_i[i] - 1));
    m2 = fmaxf(m2, fvar[i]);
  }
  l0[tid] = m0; l1[tid] = m1; l2[tid] = m2;
  __syncthreads();
  for (int off = 512; off > 0; off >>= 1) {
    if (tid < off) {
      l0[tid] = fmaxf(l0[tid], l0[tid + off]);
      l1[tid] = fmaxf(l1[tid], l1[tid + off]);
      l2[tid] = fmaxf(l2[tid], l2[tid + off]);
    }
    __syncthreads();
  }
  if (tid == 0) { maxf[0] = l0[0]; maxf[1] = l1[0]; maxf[2] = l2[0]; }
}

// ===================== per-scale hidden h = relu(dens @ Wd1^T + bd1), batched over scales =====================
__global__ __launch_bounds__(256) void h_kernel(
    const int* __restrict__ sptr, const int* __restrict__ sp_i, const float* __restrict__ fvar,
    const float* __restrict__ maxf, const float* __restrict__ Wd1,
    const float* __restrict__ bd1, f16* __restrict__ hbuf, int N, int Mp)
{
  int id = blockIdx.x * 256 + threadIdx.x;
  if (id >= N * 128) return;
  int s = blockIdx.y;
  int node = id >> 7, j = id & 127;
  float dm = maxf[0] + 1e-8f;
  float sm = maxf[1] + 1e-8f;
  float fm = maxf[2] + 1e-8f;
  float d0 = (float)(sptr[node + 1] - sptr[node]) / dm;
  float d1 = (float)(sp_i[node] - 1) / sm;
  float d2 = fvar[node] / fm;
  const float* wr = Wd1 + s * 384 + j * 3;
  float h = fmaxf(wr[0] * d0 + wr[1] * d1 + wr[2] * d2 + bd1[s * 128 + j], 0.0f);
  hbuf[(size_t)s * Mp * 128 + (size_t)node * 128 + j] = (f16)h;
}

// ===================== fp16 MFMA GEMM, scale-batched (blockIdx.z), split fp8 output =====================
__global__ __launch_bounds__(256) void gemm_bt_f16(
    const f16* __restrict__ A, int lda, long sA,
    const f16* __restrict__ B, int ldb, long sB,
    const float* __restrict__ bias, int sBias,
    void* __restrict__ Cv, int ldc, long sC, int K, int Mstore, int outMode,
    unsigned char* __restrict__ Cv2, int ldc2, long sC2, int ysplit)
{
  __shared__ f16 As[128 * 64];
  __shared__ f16 Bs[128 * 64];
  const int s = blockIdx.z;
  const int tid = threadIdx.x;
  const int lane = tid & 63;
  const int w = tid >> 6;
  const int wr = (w >> 1) * 64, wc = (w & 1) * 64;
  const int srow = tid >> 3;
  const int scol = (tid & 7) * 8;
  const f16* Ab = A + (size_t)s * sA + (size_t)(blockIdx.x * 128 + srow) * lda + scol;
  const f16* Bb = B + (size_t)s * sB + (size_t)(blockIdx.y * 128 + srow) * ldb + scol;
  char* Asl = (char*)As + tid * 16;
  char* Bsl = (char*)Bs + tid * 16;

  f32x4 acc[4][4] = {};

  for (int kt = 0; kt < K; kt += 64) {
    __syncthreads();
#pragma unroll
    for (int i = 0; i < 4; ++i) {
      gld_lds16(Ab + (size_t)i * 32 * lda + kt, Asl + i * 4096);
      gld_lds16(Bb + (size_t)i * 32 * ldb + kt, Bsl + i * 4096);
    }
    __syncthreads();
#pragma unroll
    for (int kq = 0; kq < 2; ++kq) {
      const int krd = kq * 32 + (lane >> 4) * 8;
      f16x8 af[4], bfr[4];
#pragma unroll
      for (int t = 0; t < 4; ++t) {
        af[t]  = *(const f16x8*)&As[(wr + t * 16 + (lane & 15)) * 64 + krd];
        bfr[t] = *(const f16x8*)&Bs[(wc + t * 16 + (lane & 15)) * 64 + krd];
      }
#pragma unroll
      for (int mi = 0; mi < 4; ++mi)
#pragma unroll
        for (int ni = 0; ni < 4; ++ni)
          acc[mi][ni] = __builtin_amdgcn_mfma_f32_16x16x32_f16(af[mi], bfr[ni], acc[mi][ni], 0, 0, 0);
    }
  }

  const int r0 = (lane >> 4) << 2;
  const int c0 = lane & 15;
  const bool f8p = ((int)blockIdx.y >= ysplit);
  const int cbase = f8p ? ((int)blockIdx.y - ysplit) * 128 : (int)blockIdx.y * 128;
#pragma unroll
  for (int mi = 0; mi < 4; ++mi) {
#pragma unroll
    for (int ni = 0; ni < 4; ++ni) {
      int col = cbase + wc + ni * 16 + c0;
      float bv = (!f8p && bias) ? bias[s * sBias + col] : 0.0f;
#pragma unroll
      for (int r = 0; r < 4; ++r) {
        int row = blockIdx.x * 128 + wr + mi * 16 + r0 + r;
        if (row < Mstore) {
          float v = acc[mi][ni][r] + bv;
          if (f8p) {
            unsigned pk = __builtin_amdgcn_cvt_pk_fp8_f32(v, v, 0u, false);
            Cv2[(size_t)s * sC2 + (size_t)row * ldc2 + col] = (unsigned char)(pk & 0xffu);
          } else if (outMode == 1) {
            ((f16*)Cv)[(size_t)s * sC + (size_t)row * ldc + col] = (f16)v;
          } else {
            ((float*)Cv)[(size_t)s * sC + (size_t)row * ldc + col] = v;
          }
        }
      }
    }
  }
}

// ===================== normalize df rows -> dfn (fp8), batched over scales =====================
__global__ __launch_bounds__(256) void norm_kernel(const f16* __restrict__ dfh,
                                                   unsigned* __restrict__ drec8, int N, int Mp)
{
  int wv = threadIdx.x >> 6, lane = threadIdx.x & 63;
  int node = blockIdx.x * 4 + wv;
  if (node >= N) return;
  int s = blockIdx.y;
  float4 d = ld4h(dfh + (size_t)s * Mp * 256 + (size_t)node * 256 + lane * 4);
  float ss = d.x * d.x + d.y * d.y + d.z * d.z + d.w * d.w;
  ss += __shfl_xor(ss, 1);  ss += __shfl_xor(ss, 2);  ss += __shfl_xor(ss, 4);
  ss += __shfl_xor(ss, 8);  ss += __shfl_xor(ss, 16); ss += __shfl_xor(ss, 32);
  float rn = 1.0f / fmaxf(sqrtf(ss), 1e-8f);
  drec8[(size_t)s * Mp * 64 + node * 64 + lane] = enc_fp8x4(d.x * rn, d.y * rn, d.z * rn, d.w * rn);
}

// ===================== edge attention: wave/node, slot(8)x head(8) lane layout =====================
// nrec row (per node, f16, 512): [0:256)=q [256:512)=v ; krec8/drec8: fp8 (64 u32 words per node)
__global__ __launch_bounds__(256) void edge_attn(
    const f16* __restrict__ nrec0, const unsigned* __restrict__ krec0,
    const unsigned* __restrict__ drec0, const int2* __restrict__ erec,
    const int* __restrict__ dptr, const float* __restrict__ enc_tab,
    const float* __restrict__ temp, f16* __restrict__ aggh0, int N, int Mp)
{
  int wv = threadIdx.x >> 6, lane = threadIdx.x & 63;
  int node = blockIdx.x * 4 + wv;
  if (node >= N) return;
  const int s = blockIdx.y;
  const int sshift = 7 * s;
  const f16* nrec = nrec0 + (size_t)s * Mp * 512;
  const unsigned* krec8 = krec0 + (size_t)s * Mp * 64;
  const unsigned* drec8 = drec0 + (size_t)s * Mp * 64;
  const float* enc_s = enc_tab + s * 1600;
  f16* aggh = aggh0 + (size_t)s * Mp * 256;

  const int slot = lane >> 3;   // edge slot 0..7
  const int hd   = lane & 7;    // head

  // q (f16, kept packed for fma_mix) and dfi (fp8 words) for this head's 32 dims
  f16x8 qv[4];
  unsigned diw[8];
  {
    const f16* qp = nrec + (size_t)node * 512 + hd * 32;
#pragma unroll
    for (int i = 0; i < 4; ++i) qv[i] = *(const f16x8*)(qp + i * 8);
    const unsigned* dp = drec8 + node * 64 + hd * 8;
    uint4 a = *(const uint4*)dp;
    uint4 b = *(const uint4*)(dp + 4);
    diw[0]=a.x; diw[1]=a.y; diw[2]=a.z; diw[3]=a.w;
    diw[4]=b.x; diw[5]=b.y; diw[6]=b.z; diw[7]=b.w;
  }
  const float inv_th = 0.17677669529663687f / temp[s * 8 + hd];

  float m = -1e30f, z = 0.f;
  float acc[32];
#pragma unroll
  for (int i = 0; i < 32; ++i) acc[i] = 0.f;

  int e0 = dptr[node], e1 = dptr[node + 1];
  int nit = (e1 - e0 + 7) >> 3;
  for (int it = 0; it < nit; ++it) {
    int e = e0 + it * 8 + slot;
    bool valid = e < e1;
    int2 rec = erec[valid ? e : e1 - 1];
    int src = rec.x;
    unsigned pb = (unsigned)rec.y;
    const unsigned* kp = krec8 + src * 64 + hd * 8;
    const unsigned* dp = drec8 + src * 64 + hd * 8;
    const f16* vp = nrec + (size_t)src * 512 + 256 + hd * 32;
    uint4 ka = *(const uint4*)kp;
    uint4 kb = *(const uint4*)(kp + 4);
    uint4 da = *(const uint4*)dp;
    uint4 db = *(const uint4*)(dp + 4);
    f16x8 vs0 = *(const f16x8*)vp;
    f16x8 vs1 = *(const f16x8*)(vp + 8);
    f16x8 vs2 = *(const f16x8*)(vp + 16);
    f16x8 vs3 = *(const f16x8*)(vp + 24);
    float enc = enc_s[((pb >> sshift) & 127u) * 16 + (pb >> 21)];

    unsigned kw[8] = {ka.x, ka.y, ka.z, ka.w, kb.x, kb.y, kb.z, kb.w};
    unsigned dw[8] = {da.x, da.y, da.z, da.w, db.x, db.y, db.z, db.w};
    float qk0 = 0.f, qk1 = 0.f, qk2 = 0.f, qk3 = 0.f;
    float ds0 = 0.f, ds1 = 0.f, ds2 = 0.f, ds3 = 0.f;
#pragma unroll
    for (int w = 0; w < 8; ++w) {
      float4 kf = dec_fp8x4(kw[w]);
      f16x8 qq = qv[w >> 1];
      const int b = (w & 1) * 4;
      qk0 = fmaf((float)qq[b+0], kf.x, qk0);
      qk1 = fmaf((float)qq[b+1], kf.y, qk1);
      qk2 = fmaf((float)qq[b+2], kf.z, qk2);
      qk3 = fmaf((float)qq[b+3], kf.w, qk3);
      float4 df = dec_fp8x4(dw[w]);
      float4 dd = dec_fp8x4(diw[w]);
      ds0 = fmaf(dd.x, df.x, ds0);
      ds1 = fmaf(dd.y, df.y, ds1);
      ds2 = fmaf(dd.z, df.z, ds2);
      ds3 = fmaf(dd.w, df.w, ds3);
    }
    float qk = (qk0 + qk1) + (qk2 + qk3);
    float ds = (ds0 + ds1) + (ds2 + ds3);
    // ds: full-D dot -> reduce over the 8 head-lanes of this slot
    ds += __shfl_xor(ds, 1); ds += __shfl_xor(ds, 2); ds += __shfl_xor(ds, 4);

    float sc = (qk * inv_th + enc) * (1.0f + 0.5f * ds);
    sc = valid ? sc : -1e30f;
    // deferred-max online softmax (per lane; rescale branch wave-uniform)
    if (__any(sc > m + 8.0f)) {
      float mn = fmaxf(m, sc);
      float rs = __expf(m - mn);
      z *= rs;
#pragma unroll
      for (int i = 0; i < 32; ++i) acc[i] *= rs;
      m = mn;
    }
    float p = __expf(sc - m) * (valid ? 1.0f : 0.0f);
    z += p;
#pragma unroll
    for (int j = 0; j < 8; ++j) acc[j]      = fmaf(p, (float)vs0[j], acc[j]);
#pragma unroll
    for (int j = 0; j < 8; ++j) acc[8 + j]  = fmaf(p, (float)vs1[j], acc[8 + j]);
#pragma unroll
    for (int j = 0; j < 8; ++j) acc[16 + j] = fmaf(p, (float)vs2[j], acc[16 + j]);
#pragma unroll
    for (int j = 0; j < 8; ++j) acc[24 + j] = fmaf(p, (float)vs3[j], acc[24 + j]);
  }

  // merge the 8 slots (lanes differing in bits 3..5), same head
  float M = m;
  M = fmaxf(M, __shfl_xor(M, 8));
  M = fmaxf(M, __shfl_xor(M, 16));
  M = fmaxf(M, __shfl_xor(M, 32));
  float f = __expf(m - M);
  z *= f;
  z += __shfl_xor(z, 8); z += __shfl_xor(z, 16); z += __shfl_xor(z, 32);
#pragma unroll
  for (int i = 0; i < 32; ++i) {
    float a = acc[i] * f;
    a += __shfl_xor(a, 8); a += __shfl_xor(a, 16); a += __shfl_xor(a, 32);
    acc[i] = a;
  }
  float rz = 1.0f / (z + 1e-16f);
  if (slot == 0) {
    f16* op = aggh + (size_t)node * 256 + hd * 32;
#pragma unroll
    for (int w = 0; w < 4; ++w) {
      f16x8 o;
#pragma unroll
      for (int j = 0; j < 8; ++j) o[j] = (f16)(acc[w * 8 + j] * rz);
      *(f16x8*)(op + w * 8) = o;
    }
  }
}

// ===================== host launcher =====================
extern "C" void kernel_launch(void* const* d_in, const int* in_sizes, int n_in,
                              void* d_out, int out_size, void* d_ws, size_t ws_size,
                              hipStream_t stream)
{
  const float* x      = (const float*)d_in[0];
  const float* coords = (const float*)d_in[1];
  const int*   eidx   = (const int*)  d_in[2];
  const float* Wq   = (const float*)d_in[3];
  const float* Wk   = (const float*)d_in[4];
  const float* Wv   = (const float*)d_in[5];
  const float* Wo   = (const float*)d_in[6];
  const float* bo   = (const float*)d_in[7];
  const float* temp = (const float*)d_in[8];
  const float* dist_emb = (const float*)d_in[9];
  const float* dir_emb  = (const float*)d_in[10];
  const float* Wsp1 = (const float*)d_in[11];
  const float* bsp1 = (const float*)d_in[12];
  const float* Wsp2 = (const float*)d_in[13];
  const float* bsp2 = (const float*)d_in[14];
  const float* Wd1  = (const float*)d_in[15];
  const float* bd1  = (const float*)d_in[16];
  const float* Wd2  = (const float*)d_in[17];
  const float* bd2  = (const float*)d_in[18];
  const float* Wf   = (const float*)d_in[19];
  const float* bf   = (const float*)d_in[20];
  (void)n_in; (void)out_size; (void)ws_size;

  const int N  = in_sizes[0] / 256;
  const int E  = in_sizes[2] / 2;
  const int Mp = ((N + 127) / 128) * 128;

  char* p = (char*)d_ws;
  auto alloc = [&](size_t b) -> void* {
    void* r = (void*)p;
    p += (b + 255) & ~(size_t)255;
    return r;
  };

  f16*      x_h   = (f16*)     alloc((size_t)Mp * 256 * 2);
  unsigned* x8    = (unsigned*)alloc((size_t)Mp * 256);
  f16*      nrec3 = (f16*)     alloc((size_t)3 * Mp * 512 * 2);  // q|v per node per scale
  unsigned* krec3 = (unsigned*)alloc((size_t)3 * Mp * 256);
  unsigned* drec3 = (unsigned*)alloc((size_t)3 * Mp * 256);
  f16*      hbuf3 = (f16*)     alloc((size_t)3 * Mp * 128 * 2);
  f16*      dfh3  = (f16*)     alloc((size_t)3 * Mp * 256 * 2);
  f16*      aggh3 = (f16*)     alloc((size_t)3 * Mp * 256 * 2);
  f16*      outsh = (f16*)     alloc((size_t)Mp * 768 * 2);
  f16*      wqvk  = (f16*)     alloc((size_t)3 * 768 * 256 * 2);
  f16*      wo_h  = (f16*)     alloc((size_t)3 * 256 * 256 * 2);
  f16*      wf_h  = (f16*)     alloc((size_t)256 * 768 * 2);
  f16*      wd2h  = (f16*)     alloc((size_t)3 * 256 * 128 * 2);
  float*    enc_tab = (float*) alloc((size_t)3 * 1600 * 4);
  int*    dptr = (int*)   alloc((size_t)(N + 1) * 4);
  int*    sptr = (int*)   alloc((size_t)(N + 1) * 4);
  int*    cptr = (int*)   alloc((size_t)401 * 4);
  int2*   erec = (int2*)  alloc((size_t)E * 8);
  int*    sdst = (int*)   alloc((size_t)E * 4);
  float2* scoord = (float2*)alloc((size_t)N * 8);
  float*  fvar = (float*) alloc((size_t)N * 4);
  int*    sp_i = (int*)   alloc((size_t)N * 4);
  float*  maxf = (float*) alloc(4 * 4);
  // ---- zeroed-every-call block ----
  char* z0 = p;
  int* deg_i   = (int*)alloc((size_t)N * 4);
  int* indeg_i = (int*)alloc((size_t)N * 4);
  int* fill_d  = (int*)alloc((size_t)N * 4);
  int* fill_s  = (int*)alloc((size_t)N * 4);
  int* cellcnt = (int*)alloc(400 * 4);
  int* fill_c  = (int*)alloc(400 * 4);
  size_t zbytes = (size_t)(p - z0);
  hipMemsetAsync(z0, 0, zbytes, stream);

  // 1. casts
  cast_kernel<<<2048, 256, 0, stream>>>(x, Wq, Wk, Wv, Wo, Wf, Wd2,
                                        x_h, x8, wqvk, wo_h, wf_h, wd2h, N);
  // 2. enc tables
  enc_kernel<<<(4800 + 255) / 256, 256, 0, stream>>>(dist_emb, dir_emb, Wsp1, bsp1, Wsp2, bsp2, enc_tab);
  // 3. degree + cell histograms
  hist_kernel<<<(E + 255) / 256, 256, 0, stream>>>(eidx, coords, deg_i, indeg_i, cellcnt, E, N);
  // 4. scans (3 independent blocks)
  scan_kernel<<<3, 1024, 0, stream>>>(indeg_i, deg_i, cellcnt, dptr, sptr, cptr, N);
  // 5. CSR scatter + edge bins + cell scatter
  scatter_kernel<<<(E + 255) / 256, 256, 0, stream>>>(eidx, coords, dptr, sptr, cptr,
                                                      fill_d, fill_s, fill_c, erec, sdst, scoord, E, N);
  // 6. node stats: spatial density + fvar
  node_stats_kernel<<<(N + 3) / 4, 256, 0, stream>>>(coords, scoord, cptr, x, x8,
                                                     sptr, sdst, sp_i, fvar, N);
  // 7. maxes via single-block tree reduction
  maxred_kernel<<<1, 1024, 0, stream>>>(sptr, sp_i, fvar, maxf, N);

  const int mtiles = Mp / 128;
  // 8. density hidden layer, all scales
  h_kernel<<<dim3((N * 128 + 255) / 256, 3), 256, 0, stream>>>(sptr, sp_i, fvar, maxf,
                                                               Wd1, bd1, hbuf3, N, Mp);
  // 9. df = h @ Wd2^T + bd2 (f16), all scales
  gemm_bt_f16<<<dim3(mtiles, 2, 3), 256, 0, stream>>>(hbuf3, 128, (long)Mp * 128,
                                                      wd2h, 128, 32768, bd2, 256,
                                                      dfh3, 256, (long)Mp * 256, 128, Mp, 1,
                                                      nullptr, 0, 0, 99);
  // 10. normalize -> fp8 dfn, all scales
  norm_kernel<<<dim3((N + 3) / 4, 3), 256, 0, stream>>>(dfh3, drec3, N, Mp);
  // 11. q,v (f16) and k (fp8) in one split-output GEMM, all scales
  gemm_bt_f16<<<dim3(mtiles, 6, 3), 256, 0, stream>>>(x_h, 256, 0,
                                                      wqvk, 256, 196608, nullptr, 0,
                                                      nrec3, 512, (long)Mp * 512, 256, Mp, 1,
                                                      (unsigned char*)krec3, 256, (long)Mp * 256, 4);
  // 12. edge attention + scatter softmax + aggregate, all scales
  edge_attn<<<dim3((N + 3) / 4, 3), 256, 0, stream>>>(nrec3, krec3, drec3, erec, dptr,
                                                      enc_tab, temp, aggh3, N, Mp);
  // 13. output projection into concat buffer, all scales
  gemm_bt_f16<<<dim3(mtiles, 2, 3), 256, 0, stream>>>(aggh3, 256, (long)Mp * 256,
                                                      wo_h, 256, 65536, bo, 256,
                                                      outsh, 768, 256, 256, Mp, 1,
                                                      nullptr, 0, 0, 99);
  // 14. fusion GEMM -> d_out (f32), guard rows < N
  gemm_bt_f16<<<dim3(mtiles, 2, 1), 256, 0, stream>>>(outsh, 768, 0,
                                                      wf_h, 768, 0, bf, 0,
                                                      d_out, 256, 0, 768, N, 0,
                                                      nullptr, 0, 0, 99);
}